// Round 4
// baseline (17272.200 us; speedup 1.0000x reference)
//
#include <hip/hip_runtime.h>
#include <hip/hip_bf16.h>
#include <math.h>
#include <stdint.h>

#define CC 66      // channels = J*DIMS
#define TT 100     // time steps
#define JJ 22      // joints
#define HH 8       // heads
#define HD 64      // head dim
#define EE 512     // embed
#define CPAD 101   // comb LDS stride (odd -> conflict-free columns)

// One block per batch element, 128 threads. fp32 everywhere (inputs fp32,
// output fp32 — R3 post-mortem: harness reads d_out as float for fp32 refs).
__global__ __launch_bounds__(128) void k_fused(
    const float* __restrict__ x, const float* __restrict__ adj,
    const float* __restrict__ sadj, const float* __restrict__ tmask,
    const float* __restrict__ tadj,
    const float* __restrict__ st_wq, const float* __restrict__ st_bq,
    const float* __restrict__ st_wk, const float* __restrict__ st_bk,
    const float* __restrict__ st_wv, const float* __restrict__ st_bv,
    const float* __restrict__ st_wo, const float* __restrict__ st_bo,
    const float* __restrict__ ts_wq, const float* __restrict__ ts_bq,
    const float* __restrict__ ts_wk, const float* __restrict__ ts_bk,
    const float* __restrict__ ts_wv, const float* __restrict__ ts_bv,
    const float* __restrict__ ts_wo, const float* __restrict__ ts_bo,
    const float* __restrict__ alpha, const float* __restrict__ beta,
    const float* __restrict__ fcw, const float* __restrict__ fcb,
    float* __restrict__ out)
{
  __shared__ float s_sp[CC*TT];                    // 26400 B spatial tokens
  __shared__ float s_tp[CC*TT];                    // 26400 B temporal tokens
  __shared__ __align__(16) float s_kv[2*TT*HD];    // 51200 B K/V; also M^T; also fc_w^T
  __shared__ float s_comb[CC*CPAD];                // 26664 B accumulator; also x staging
  __shared__ float s_A[JJ*JJ];                     // 1936 B
  __shared__ float s_dis[JJ];                      // 88 B   (total ~132.7 KB -> 1 block/CU)

  const int b = blockIdx.x, tid = threadIdx.x;
  const long bb = (long)b * (CC*TT);
  float* s_xs = s_comb;               // x staging, 26400 <= 26664
  float* s_Mt = s_kv;                 // M^T staging, 40000 <= 51200

  // ---------------- P0: stage x, M^T, degree norms ----------------
  if (tid < JJ) {
    float dsum = 0.f;
    for (int i = 0; i < JJ; ++i) dsum += adj[tid*JJ + i];
    s_dis[tid] = dsum > 0.f ? rsqrtf(dsum) : 0.f;
  }
  for (int o = tid; o < CC*TT; o += 128) s_xs[o] = x[bb + o];
  for (int o = tid; o < TT*TT; o += 128) {
    int f = o / TT, t = o - f*TT;
    s_Mt[t*TT + f] = tadj[o] * tmask[o];
  }
  __syncthreads();
  for (int o = tid; o < JJ*JJ; o += 128) {
    int v = o / JJ, j = o - v*JJ;
    s_A[o] = sadj[o] * adj[o] * s_dis[v] * s_dis[j];
  }
  __syncthreads();

  // ---------------- P1: graph convs into LDS ----------------
  // spatial[c][t] = sum_j A[v][j] * x[(j*3+dd)][t],  c = v*3+dd
  for (int o = tid; o < CC*TT; o += 128) {
    int c = o / TT, t = o - c*TT, v = c / 3, dd = c - v*3;
    float acc = 0.f;
    for (int j = 0; j < JJ; ++j) acc += s_A[v*JJ + j] * s_xs[(j*3 + dd)*TT + t];
    s_sp[o] = acc;
  }
  // temporal[n][f] = sum_t x[n][t] * M[f][t]
  for (int o = tid; o < CC*TT; o += 128) {
    int n = o / TT, f = o - n*TT;
    float a0 = 0.f, a1 = 0.f;
    for (int t = 0; t < TT; t += 2) {
      a0 += s_xs[n*TT + t    ] * s_Mt[(t    )*TT + f];
      a1 += s_xs[n*TT + t + 1] * s_Mt[(t + 1)*TT + f];
    }
    s_tp[o] = a0 + a1;
  }
  __syncthreads();   // convs done: s_xs (s_comb) and s_Mt (s_kv) now free

  // init comb accumulator with both output biases folded in
  for (int o = tid; o < CC*TT; o += 128) {
    int c = o / TT, t = o - c*TT;
    s_comb[c*CPAD + t] = st_bo[c] + ts_bo[t];
  }

  // ---------------- P2: attn1 (queries=100 spatial tokens, keys=66 temporal) ----------------
  {
    float* s_k = s_kv;
    float* s_v = s_kv + TT*HD;
    for (int h = 0; h < HH; ++h) {
      const int base = h*HD;
      __syncthreads();                 // protects s_kv reuse + s_comb init at h=0
      {   // K[k][d] = bk + sum_t tp[k][t]*wk[t][base+d]
        const int d = tid & 63, krow = tid >> 6;
        for (int kk = 0; kk < CC/2; ++kk) {
          int k = kk*2 + krow;
          float aK = st_bk[base + d], aV = st_bv[base + d];
          const float* tr = s_tp + k*TT;
          for (int t = 0; t < TT; ++t) {
            float a = tr[t];
            aK += a * st_wk[(long)t*EE + base + d];
            aV += a * st_wv[(long)t*EE + base + d];
          }
          s_k[k*HD + d] = aK;
          s_v[k*HD + d] = aV;
        }
      }
      __syncthreads();
      if (tid < TT) {
        const int q = tid;
        float qv[HD];
        #pragma unroll
        for (int d = 0; d < HD; ++d) qv[d] = st_bq[base + d];
        for (int c = 0; c < CC; ++c) {
          float a = s_sp[c*TT + q];
          const float* wr = st_wq + (long)c*EE + base;
          #pragma unroll
          for (int d = 0; d < HD; ++d) qv[d] += a * wr[d];
        }
        float m = -INFINITY, l = 0.f, ov[HD];
        #pragma unroll
        for (int d = 0; d < HD; ++d) ov[d] = 0.f;
        for (int k = 0; k < CC; ++k) {
          const float4* kr4 = (const float4*)(s_k + k*HD);
          float s0=0.f,s1=0.f,s2=0.f,s3=0.f;
          #pragma unroll
          for (int i = 0; i < 16; ++i) {
            float4 kk4 = kr4[i];
            s0 += qv[4*i  ]*kk4.x; s1 += qv[4*i+1]*kk4.y;
            s2 += qv[4*i+2]*kk4.z; s3 += qv[4*i+3]*kk4.w;
          }
          float s  = (s0+s1+s2+s3) * 0.125f;
          float mn = fmaxf(m, s);
          float corr = __expf(m - mn);
          float p    = __expf(s - mn);
          l = l*corr + p;
          const float4* vr4 = (const float4*)(s_v + k*HD);
          #pragma unroll
          for (int i = 0; i < 16; ++i) {
            float4 vv4 = vr4[i];
            ov[4*i  ] = ov[4*i  ]*corr + p*vv4.x;
            ov[4*i+1] = ov[4*i+1]*corr + p*vv4.y;
            ov[4*i+2] = ov[4*i+2]*corr + p*vv4.z;
            ov[4*i+3] = ov[4*i+3]*corr + p*vv4.w;
          }
          m = mn;
        }
        float rl = 1.f/l;
        #pragma unroll
        for (int d = 0; d < HD; ++d) ov[d] *= rl;
        // comb[c][q] += sum_d ov[d]*wo[base+d][c]
        for (int c = 0; c < CC; ++c) {
          const float* wr = st_wo + (long)base*CC + c;
          float a0=0.f,a1=0.f,a2=0.f,a3=0.f;
          #pragma unroll
          for (int d = 0; d < HD; d += 4) {
            a0 += ov[d  ]*wr[(long)(d  )*CC]; a1 += ov[d+1]*wr[(long)(d+1)*CC];
            a2 += ov[d+2]*wr[(long)(d+2)*CC]; a3 += ov[d+3]*wr[(long)(d+3)*CC];
          }
          s_comb[c*CPAD + q] += a0+a1+a2+a3;
        }
      }
    }
  }

  // ---------------- P3: attn2 (queries=66 temporal tokens, keys=100 spatial) ----------------
  {
    float* s_k = s_kv;
    float* s_v = s_kv + TT*HD;
    for (int h = 0; h < HH; ++h) {
      const int base = h*HD;
      __syncthreads();                 // protects s_kv reuse from attn1 reads
      {   // K[k][d] = bk + sum_c sp[c][k]*wk[c][base+d]
        const int d = tid & 63, krow = tid >> 6;
        for (int kk = 0; kk < TT/2; ++kk) {
          int k = kk*2 + krow;
          float aK = ts_bk[base + d], aV = ts_bv[base + d];
          for (int c = 0; c < CC; ++c) {
            float a = s_sp[c*TT + k];
            aK += a * ts_wk[(long)c*EE + base + d];
            aV += a * ts_wv[(long)c*EE + base + d];
          }
          s_k[k*HD + d] = aK;
          s_v[k*HD + d] = aV;
        }
      }
      __syncthreads();
      if (tid < CC) {
        const int q = tid;
        float qv[HD];
        #pragma unroll
        for (int d = 0; d < HD; ++d) qv[d] = ts_bq[base + d];
        const float* tr = s_tp + q*TT;
        for (int t = 0; t < TT; ++t) {
          float a = tr[t];
          const float* wr = ts_wq + (long)t*EE + base;
          #pragma unroll
          for (int d = 0; d < HD; ++d) qv[d] += a * wr[d];
        }
        float m = -INFINITY, l = 0.f, ov[HD];
        #pragma unroll
        for (int d = 0; d < HD; ++d) ov[d] = 0.f;
        for (int k = 0; k < TT; ++k) {
          const float4* kr4 = (const float4*)(s_k + k*HD);
          float s0=0.f,s1=0.f,s2=0.f,s3=0.f;
          #pragma unroll
          for (int i = 0; i < 16; ++i) {
            float4 kk4 = kr4[i];
            s0 += qv[4*i  ]*kk4.x; s1 += qv[4*i+1]*kk4.y;
            s2 += qv[4*i+2]*kk4.z; s3 += qv[4*i+3]*kk4.w;
          }
          float s  = (s0+s1+s2+s3) * 0.125f;
          float mn = fmaxf(m, s);
          float corr = __expf(m - mn);
          float p    = __expf(s - mn);
          l = l*corr + p;
          const float4* vr4 = (const float4*)(s_v + k*HD);
          #pragma unroll
          for (int i = 0; i < 16; ++i) {
            float4 vv4 = vr4[i];
            ov[4*i  ] = ov[4*i  ]*corr + p*vv4.x;
            ov[4*i+1] = ov[4*i+1]*corr + p*vv4.y;
            ov[4*i+2] = ov[4*i+2]*corr + p*vv4.z;
            ov[4*i+3] = ov[4*i+3]*corr + p*vv4.w;
          }
          m = mn;
        }
        float rl = 1.f/l;
        #pragma unroll
        for (int d = 0; d < HD; ++d) ov[d] *= rl;
        // comb[q][t] += sum_d ov[d]*wo[base+d][t]
        for (int t = 0; t < TT; ++t) {
          const float* wr = ts_wo + (long)base*TT + t;
          float a0=0.f,a1=0.f,a2=0.f,a3=0.f;
          #pragma unroll
          for (int d = 0; d < HD; d += 4) {
            a0 += ov[d  ]*wr[(long)(d  )*TT]; a1 += ov[d+1]*wr[(long)(d+1)*TT];
            a2 += ov[d+2]*wr[(long)(d+2)*TT]; a3 += ov[d+3]*wr[(long)(d+3)*TT];
          }
          s_comb[q*CPAD + t] += a0+a1+a2+a3;
        }
      }
    }
  }
  __syncthreads();

  // ---------------- P4: LN over channels + residual + FC over T + tanh ----------------
  if (tid < TT) {
    const int t = tid;
    float mean = 0.f;
    for (int c = 0; c < CC; ++c) mean += s_comb[c*CPAD + t];
    mean *= (1.f/CC);
    float var = 0.f;
    for (int c = 0; c < CC; ++c) { float dv = s_comb[c*CPAD + t] - mean; var += dv*dv; }
    var *= (1.f/CC);
    float rstd = 1.f / sqrtf(var + 1e-5f);
    for (int c = 0; c < CC; ++c) {
      float y = (s_comb[c*CPAD + t] - mean) * rstd * alpha[c] + beta[c];
      s_comb[c*CPAD + t] = y + x[bb + c*TT + t];
    }
  }
  __syncthreads();

  // stage fc_w transposed into s_kv (attn done with it)
  float* s_w = s_kv;
  for (int o = tid; o < TT*TT; o += 128) {
    int f = o / TT, t = o - f*TT;
    s_w[t*TT + f] = fcw[o];
  }
  __syncthreads();

  // out[c][f] = tanh(fcb[f] + sum_t z[c][t]*fcw[f][t])
  for (int o = tid; o < CC*TT; o += 128) {
    int c = o / TT, f = o - c*TT;
    const float* cr = s_comb + c*CPAD;
    float a0 = 0.f, a1 = 0.f;
    for (int t = 0; t < TT; t += 2) {
      a0 += cr[t    ] * s_w[(t    )*TT + f];
      a1 += cr[t + 1] * s_w[(t + 1)*TT + f];
    }
    out[bb + o] = tanhf(a0 + a1 + fcb[f]);
  }
}

// ---------------------------------------------------------------- launch
extern "C" void kernel_launch(void* const* d_in, const int* in_sizes, int n_in,
                              void* d_out, int out_size, void* d_ws, size_t ws_size,
                              hipStream_t stream) {
  const float* x     = (const float*)d_in[0];
  const float* adj   = (const float*)d_in[1];
  const float* sadj  = (const float*)d_in[2];
  const float* tmask = (const float*)d_in[3];
  const float* tadj  = (const float*)d_in[4];
  const float* st_wq = (const float*)d_in[5];  const float* st_bq = (const float*)d_in[6];
  const float* st_wk = (const float*)d_in[7];  const float* st_bk = (const float*)d_in[8];
  const float* st_wv = (const float*)d_in[9];  const float* st_bv = (const float*)d_in[10];
  const float* st_wo = (const float*)d_in[11]; const float* st_bo = (const float*)d_in[12];
  const float* ts_wq = (const float*)d_in[13]; const float* ts_bq = (const float*)d_in[14];
  const float* ts_wk = (const float*)d_in[15]; const float* ts_bk = (const float*)d_in[16];
  const float* ts_wv = (const float*)d_in[17]; const float* ts_bv = (const float*)d_in[18];
  const float* ts_wo = (const float*)d_in[19]; const float* ts_bo = (const float*)d_in[20];
  const float* alpha = (const float*)d_in[21]; const float* beta  = (const float*)d_in[22];
  const float* fcw   = (const float*)d_in[23]; const float* fcb   = (const float*)d_in[24];
  float* out = (float*)d_out;

  const int B = in_sizes[0] / (CC*TT);

  k_fused<<<B, 128, 0, stream>>>(x, adj, sadj, tmask, tadj,
                                 st_wq, st_bq, st_wk, st_bk, st_wv, st_bv, st_wo, st_bo,
                                 ts_wq, ts_bq, ts_wk, ts_bk, ts_wv, ts_bv, ts_wo, ts_bo,
                                 alpha, beta, fcw, fcb, out);
}

// Round 5
// 6603.413 us; speedup vs baseline: 2.6156x; 2.6156x over previous
//
#include <hip/hip_runtime.h>
#include <hip/hip_bf16.h>
#include <math.h>
#include <stdint.h>

typedef __hip_bfloat16 bf16;

#define CC 66      // channels = J*DIMS
#define TT 100     // time steps
#define JJ 22      // joints
#define HH 8       // heads
#define HD 64      // head dim
#define EE 512     // embed
#define CPAD 101   // comb LDS stride (odd -> conflict-free)

__device__ __forceinline__ float b2f(bf16 v){ return __bfloat162float(v); }
__device__ __forceinline__ bf16 f2b(float v){ return __float2bfloat16(v); }

// ---------------------------------------------------------------- k_prep
// B blocks x 256: sp = A@x (joint mix), tp = x@M^T (banded time mix) -> ws bf16
__global__ __launch_bounds__(256) void k_prep(
    const float* __restrict__ x, const float* __restrict__ adj,
    const float* __restrict__ sadj, const float* __restrict__ tmask,
    const float* __restrict__ tadj,
    bf16* __restrict__ sp_g, bf16* __restrict__ tp_g)
{
  __shared__ float s_x[CC*TT];    // 26400
  __shared__ float s_Mt[TT*TT];   // 40000
  __shared__ float s_A[JJ*JJ];
  __shared__ float s_dis[JJ];     // total ~68.5 KB -> 2 blocks/CU
  const int b = blockIdx.x, tid = threadIdx.x;
  const long bb = (long)b * (CC*TT);

  if (tid < JJ) {
    float dsum = 0.f;
    for (int i = 0; i < JJ; ++i) dsum += adj[tid*JJ + i];
    s_dis[tid] = dsum > 0.f ? rsqrtf(dsum) : 0.f;
  }
  for (int o = tid; o < CC*TT; o += 256) s_x[o] = x[bb + o];
  for (int o = tid; o < TT*TT; o += 256) {
    int f = o / TT, t = o - f*TT;
    s_Mt[t*TT + f] = tadj[o] * tmask[o];
  }
  __syncthreads();
  for (int o = tid; o < JJ*JJ; o += 256) {
    int v = o / JJ, j = o - v*JJ;
    s_A[o] = sadj[o] * adj[o] * s_dis[v] * s_dis[j];
  }
  __syncthreads();

  for (int o = tid; o < CC*TT; o += 256) {
    int c = o / TT, t = o - c*TT, v = c / 3, dd = c - v*3;
    float acc = 0.f;
    for (int j = 0; j < JJ; ++j) acc += s_A[v*JJ + j] * s_x[(j*3 + dd)*TT + t];
    sp_g[bb + o] = f2b(acc);
  }
  for (int o = tid; o < CC*TT; o += 256) {
    int n = o / TT, f = o - n*TT;
    float a0 = 0.f, a1 = 0.f;
    for (int t = 0; t < TT; t += 2) {
      a0 += s_x[n*TT + t    ] * s_Mt[(t    )*TT + f];
      a1 += s_x[n*TT + t + 1] * s_Mt[(t + 1)*TT + f];
    }
    tp_g[bb + o] = f2b(a0 + a1);
  }
}

// ---------------------------------------------------------------- k_attn
// 2B blocks x 256: block (b, a): a=0 -> attn1 (100 queries over 66 keys),
// a=1 -> attn2 (66 queries over 100 keys). atomicAdd partial out-proj to comb.
__global__ __launch_bounds__(256) void k_attn(
    const bf16* __restrict__ sp_gg, const bf16* __restrict__ tp_gg,
    const float* __restrict__ st_wq, const float* __restrict__ st_bq,
    const float* __restrict__ st_wk, const float* __restrict__ st_bk,
    const float* __restrict__ st_wv, const float* __restrict__ st_bv,
    const float* __restrict__ st_wo,
    const float* __restrict__ ts_wq, const float* __restrict__ ts_bq,
    const float* __restrict__ ts_wk, const float* __restrict__ ts_bk,
    const float* __restrict__ ts_wv, const float* __restrict__ ts_bv,
    const float* __restrict__ ts_wo,
    float* __restrict__ comb_g)
{
  __shared__ bf16  s_sp[CC*TT];     // 13200
  __shared__ bf16  s_tp[CC*TT];     // 13200
  __shared__ bf16  s_k[TT*HD];      // 12800
  __shared__ bf16  s_v[TT*HD];      // 12800
  __shared__ float s_comb[CC*CPAD]; // 26664  -> total 78.7 KB -> 2 blocks/CU
  const int bid = blockIdx.x, tid = threadIdx.x;
  const int b = bid >> 1, a = bid & 1;
  const long bb = (long)b * (CC*TT);

  { // stage tokens (dword copies) + zero accumulator
    const uint32_t* spu = (const uint32_t*)(sp_gg + bb);
    const uint32_t* tpu = (const uint32_t*)(tp_gg + bb);
    uint32_t* dsp = (uint32_t*)s_sp; uint32_t* dtp = (uint32_t*)s_tp;
    for (int o = tid; o < CC*TT/2; o += 256) { dsp[o] = spu[o]; dtp[o] = tpu[o]; }
    for (int o = tid; o < CC*CPAD; o += 256) s_comb[o] = 0.f;
  }

  const int d = tid & 63, r = tid >> 6;   // r = wave id (0..3)

  if (a == 0) {
    // ================= attn1: K/V from temporal (66 rows), 100 queries ====
    for (int h = 0; h < HH; ++h) {
      const int base = h*HD;
      __syncthreads();                  // staging done / prev head's reads done
      { // K/V build: thread owns (d, rows 4j+r). 34 FMA : 2 global loads per t.
        float accK[17], accV[17];
        #pragma unroll
        for (int j = 0; j < 17; ++j) { accK[j] = 0.f; accV[j] = 0.f; }
        for (int t = 0; t < TT; ++t) {
          float wk_ = st_wk[(long)t*EE + base + d];
          float wv_ = st_wv[(long)t*EE + base + d];
          #pragma unroll
          for (int j = 0; j < 17; ++j) {
            int k = 4*j + r; int kk = (k < CC) ? k : 0;
            float av = b2f(s_tp[kk*TT + t]);      // wave-uniform broadcast
            accK[j] += av*wk_; accV[j] += av*wv_;
          }
        }
        float bk_ = st_bk[base + d], bv_ = st_bv[base + d];
        #pragma unroll
        for (int j = 0; j < 17; ++j) {
          int k = 4*j + r;
          if (k < CC) { s_k[k*HD + d] = f2b(bk_ + accK[j]);
                        s_v[k*HD + d] = f2b(bv_ + accV[j]); }
        }
      }
      __syncthreads();
      if (tid < 2*TT) {                 // 2 threads per query, each owns 32 dims
        const int q = tid >> 1, off = (tid & 1)*32;
        float qv[32];
        #pragma unroll
        for (int i = 0; i < 32; ++i) qv[i] = st_bq[base + off + i];
        for (int c = 0; c < CC; ++c) {
          float av = b2f(s_sp[c*TT + q]);
          const float4* w4 = (const float4*)(st_wq + (long)c*EE + base + off);
          #pragma unroll
          for (int i8 = 0; i8 < 8; ++i8) {
            float4 w = w4[i8];
            qv[4*i8  ] += av*w.x; qv[4*i8+1] += av*w.y;
            qv[4*i8+2] += av*w.z; qv[4*i8+3] += av*w.w;
          }
        }
        float m = -INFINITY, l = 0.f, ov[32];
        #pragma unroll
        for (int i = 0; i < 32; ++i) ov[i] = 0.f;
        for (int k = 0; k < CC; ++k) {
          const bf16* kr = s_k + k*HD + off;
          float s0=0.f,s1=0.f,s2=0.f,s3=0.f;
          #pragma unroll
          for (int i = 0; i < 32; i += 4) {
            s0 += qv[i  ]*b2f(kr[i  ]); s1 += qv[i+1]*b2f(kr[i+1]);
            s2 += qv[i+2]*b2f(kr[i+2]); s3 += qv[i+3]*b2f(kr[i+3]);
          }
          float s = s0+s1+s2+s3;
          s += __shfl_xor(s, 1);        // combine half-dots
          s *= 0.125f;
          float mn = fmaxf(m, s);
          float corr = __expf(m - mn), p = __expf(s - mn);
          l = l*corr + p;
          const bf16* vr = s_v + k*HD + off;
          #pragma unroll
          for (int i = 0; i < 32; ++i) ov[i] = ov[i]*corr + p*b2f(vr[i]);
          m = mn;
        }
        float rl = 1.f/l;
        #pragma unroll
        for (int i = 0; i < 32; ++i) ov[i] *= rl;
        for (int c = 0; c < CC; ++c) {
          const float* wr = st_wo + (long)(base + off)*CC + c;
          float p0=0.f,p1=0.f,p2=0.f,p3=0.f;
          #pragma unroll
          for (int i = 0; i < 32; i += 4) {
            p0 += ov[i  ]*wr[(long)(i  )*CC]; p1 += ov[i+1]*wr[(long)(i+1)*CC];
            p2 += ov[i+2]*wr[(long)(i+2)*CC]; p3 += ov[i+3]*wr[(long)(i+3)*CC];
          }
          float pr = p0+p1+p2+p3;
          pr += __shfl_xor(pr, 1);
          if ((tid & 1) == 0) s_comb[c*CPAD + q] += pr;
        }
      }
    }
  } else {
    // ================= attn2: K/V from spatial (100 rows), 66 queries =====
    for (int h = 0; h < HH; ++h) {
      const int base = h*HD;
      __syncthreads();
      { // K/V build: 50 FMA : 2 loads per c
        float accK[25], accV[25];
        #pragma unroll
        for (int j = 0; j < 25; ++j) { accK[j] = 0.f; accV[j] = 0.f; }
        for (int c = 0; c < CC; ++c) {
          float wk_ = ts_wk[(long)c*EE + base + d];
          float wv_ = ts_wv[(long)c*EE + base + d];
          #pragma unroll
          for (int j = 0; j < 25; ++j) {
            float av = b2f(s_sp[c*TT + 4*j + r]);
            accK[j] += av*wk_; accV[j] += av*wv_;
          }
        }
        float bk_ = ts_bk[base + d], bv_ = ts_bv[base + d];
        #pragma unroll
        for (int j = 0; j < 25; ++j) {
          int k = 4*j + r;
          s_k[k*HD + d] = f2b(bk_ + accK[j]);
          s_v[k*HD + d] = f2b(bv_ + accV[j]);
        }
      }
      __syncthreads();
      if (tid < 2*CC) {
        const int q = tid >> 1, off = (tid & 1)*32;
        float qv[32];
        #pragma unroll
        for (int i = 0; i < 32; ++i) qv[i] = ts_bq[base + off + i];
        for (int t = 0; t < TT; ++t) {
          float av = b2f(s_tp[q*TT + t]);
          const float4* w4 = (const float4*)(ts_wq + (long)t*EE + base + off);
          #pragma unroll
          for (int i8 = 0; i8 < 8; ++i8) {
            float4 w = w4[i8];
            qv[4*i8  ] += av*w.x; qv[4*i8+1] += av*w.y;
            qv[4*i8+2] += av*w.z; qv[4*i8+3] += av*w.w;
          }
        }
        float m = -INFINITY, l = 0.f, ov[32];
        #pragma unroll
        for (int i = 0; i < 32; ++i) ov[i] = 0.f;
        for (int k = 0; k < TT; ++k) {
          const bf16* kr = s_k + k*HD + off;
          float s0=0.f,s1=0.f,s2=0.f,s3=0.f;
          #pragma unroll
          for (int i = 0; i < 32; i += 4) {
            s0 += qv[i  ]*b2f(kr[i  ]); s1 += qv[i+1]*b2f(kr[i+1]);
            s2 += qv[i+2]*b2f(kr[i+2]); s3 += qv[i+3]*b2f(kr[i+3]);
          }
          float s = s0+s1+s2+s3;
          s += __shfl_xor(s, 1);
          s *= 0.125f;
          float mn = fmaxf(m, s);
          float corr = __expf(m - mn), p = __expf(s - mn);
          l = l*corr + p;
          const bf16* vr = s_v + k*HD + off;
          #pragma unroll
          for (int i = 0; i < 32; ++i) ov[i] = ov[i]*corr + p*b2f(vr[i]);
          m = mn;
        }
        float rl = 1.f/l;
        #pragma unroll
        for (int i = 0; i < 32; ++i) ov[i] *= rl;
        for (int t = 0; t < TT; ++t) {
          const float* wr = ts_wo + (long)(base + off)*TT + t;
          float p0=0.f,p1=0.f,p2=0.f,p3=0.f;
          #pragma unroll
          for (int i = 0; i < 32; i += 4) {
            p0 += ov[i  ]*wr[(long)(i  )*TT]; p1 += ov[i+1]*wr[(long)(i+1)*TT];
            p2 += ov[i+2]*wr[(long)(i+2)*TT]; p3 += ov[i+3]*wr[(long)(i+3)*TT];
          }
          float pr = p0+p1+p2+p3;
          pr += __shfl_xor(pr, 1);
          if ((tid & 1) == 0) s_comb[q*CPAD + t] += pr;
        }
      }
    }
  }
  __syncthreads();

  float* cg = comb_g + bb;
  for (int o = tid; o < CC*TT; o += 256) {
    int c = o / TT, t = o - c*TT;
    atomicAdd(&cg[o], s_comb[c*CPAD + t]);
  }
}

// ---------------------------------------------------------------- k_epi
// B blocks x 256: +biases, LN over channels, +x residual, FC over T, tanh.
__global__ __launch_bounds__(256) void k_epi(
    const float* __restrict__ comb_g, const float* __restrict__ x,
    const float* __restrict__ st_bo, const float* __restrict__ ts_bo,
    const float* __restrict__ alpha, const float* __restrict__ beta,
    const float* __restrict__ fcw, const float* __restrict__ fcb,
    float* __restrict__ out)
{
  __shared__ float s_cb[CC*CPAD];   // 26664
  __shared__ float s_w[TT*TT];      // 40000 -> total ~67 KB -> 2 blocks/CU
  const int b = blockIdx.x, tid = threadIdx.x;
  const long bb = (long)b * (CC*TT);

  for (int o = tid; o < CC*TT; o += 256) {
    int c = o / TT, t = o - c*TT;
    s_cb[c*CPAD + t] = comb_g[bb + o] + st_bo[c] + ts_bo[t];
  }
  for (int o = tid; o < TT*TT; o += 256) {
    int f = o / TT, t = o - f*TT;
    s_w[t*TT + f] = fcw[o];
  }
  __syncthreads();
  if (tid < TT) {
    const int t = tid;
    float mean = 0.f;
    for (int c = 0; c < CC; ++c) mean += s_cb[c*CPAD + t];
    mean *= (1.f/CC);
    float var = 0.f;
    for (int c = 0; c < CC; ++c) { float dv = s_cb[c*CPAD + t] - mean; var += dv*dv; }
    var *= (1.f/CC);
    float rstd = 1.f / sqrtf(var + 1e-5f);
    for (int c = 0; c < CC; ++c) {
      float y = (s_cb[c*CPAD + t] - mean) * rstd * alpha[c] + beta[c];
      s_cb[c*CPAD + t] = y + x[bb + c*TT + t];
    }
  }
  __syncthreads();
  for (int o = tid; o < CC*TT; o += 256) {
    int c = o / TT, f = o - c*TT;
    const float* cr = s_cb + c*CPAD;
    float a0 = 0.f, a1 = 0.f;
    for (int t = 0; t < TT; t += 2) {
      a0 += cr[t    ] * s_w[(t    )*TT + f];
      a1 += cr[t + 1] * s_w[(t + 1)*TT + f];
    }
    out[bb + o] = tanhf(a0 + a1 + fcb[f]);
  }
}

// ---------------------------------------------------------------- R4 fallback
// (proven-correct monolithic kernel; used only if ws_size < 54 MB)
__global__ __launch_bounds__(128) void k_fused(
    const float* __restrict__ x, const float* __restrict__ adj,
    const float* __restrict__ sadj, const float* __restrict__ tmask,
    const float* __restrict__ tadj,
    const float* __restrict__ st_wq, const float* __restrict__ st_bq,
    const float* __restrict__ st_wk, const float* __restrict__ st_bk,
    const float* __restrict__ st_wv, const float* __restrict__ st_bv,
    const float* __restrict__ st_wo, const float* __restrict__ st_bo,
    const float* __restrict__ ts_wq, const float* __restrict__ ts_bq,
    const float* __restrict__ ts_wk, const float* __restrict__ ts_bk,
    const float* __restrict__ ts_wv, const float* __restrict__ ts_bv,
    const float* __restrict__ ts_wo, const float* __restrict__ ts_bo,
    const float* __restrict__ alpha, const float* __restrict__ beta,
    const float* __restrict__ fcw, const float* __restrict__ fcb,
    float* __restrict__ out)
{
  __shared__ float s_sp[CC*TT];
  __shared__ float s_tp[CC*TT];
  __shared__ __align__(16) float s_kv[2*TT*HD];
  __shared__ float s_comb[CC*CPAD];
  __shared__ float s_A[JJ*JJ];
  __shared__ float s_dis[JJ];

  const int b = blockIdx.x, tid = threadIdx.x;
  const long bb = (long)b * (CC*TT);
  float* s_xs = s_comb;
  float* s_Mt = s_kv;

  if (tid < JJ) {
    float dsum = 0.f;
    for (int i = 0; i < JJ; ++i) dsum += adj[tid*JJ + i];
    s_dis[tid] = dsum > 0.f ? rsqrtf(dsum) : 0.f;
  }
  for (int o = tid; o < CC*TT; o += 128) s_xs[o] = x[bb + o];
  for (int o = tid; o < TT*TT; o += 128) {
    int f = o / TT, t = o - f*TT;
    s_Mt[t*TT + f] = tadj[o] * tmask[o];
  }
  __syncthreads();
  for (int o = tid; o < JJ*JJ; o += 128) {
    int v = o / JJ, j = o - v*JJ;
    s_A[o] = sadj[o] * adj[o] * s_dis[v] * s_dis[j];
  }
  __syncthreads();

  for (int o = tid; o < CC*TT; o += 128) {
    int c = o / TT, t = o - c*TT, v = c / 3, dd = c - v*3;
    float acc = 0.f;
    for (int j = 0; j < JJ; ++j) acc += s_A[v*JJ + j] * s_xs[(j*3 + dd)*TT + t];
    s_sp[o] = acc;
  }
  for (int o = tid; o < CC*TT; o += 128) {
    int n = o / TT, f = o - n*TT;
    float a0 = 0.f, a1 = 0.f;
    for (int t = 0; t < TT; t += 2) {
      a0 += s_xs[n*TT + t    ] * s_Mt[(t    )*TT + f];
      a1 += s_xs[n*TT + t + 1] * s_Mt[(t + 1)*TT + f];
    }
    s_tp[o] = a0 + a1;
  }
  __syncthreads();

  for (int o = tid; o < CC*TT; o += 128) {
    int c = o / TT, t = o - c*TT;
    s_comb[c*CPAD + t] = st_bo[c] + ts_bo[t];
  }

  {
    float* s_k = s_kv;
    float* s_v = s_kv + TT*HD;
    for (int h = 0; h < HH; ++h) {
      const int base = h*HD;
      __syncthreads();
      {
        const int d = tid & 63, krow = tid >> 6;
        for (int kk = 0; kk < CC/2; ++kk) {
          int k = kk*2 + krow;
          float aK = st_bk[base + d], aV = st_bv[base + d];
          const float* tr = s_tp + k*TT;
          for (int t = 0; t < TT; ++t) {
            float a = tr[t];
            aK += a * st_wk[(long)t*EE + base + d];
            aV += a * st_wv[(long)t*EE + base + d];
          }
          s_k[k*HD + d] = aK;
          s_v[k*HD + d] = aV;
        }
      }
      __syncthreads();
      if (tid < TT) {
        const int q = tid;
        float qv[HD];
        #pragma unroll
        for (int d = 0; d < HD; ++d) qv[d] = st_bq[base + d];
        for (int c = 0; c < CC; ++c) {
          float a = s_sp[c*TT + q];
          const float* wr = st_wq + (long)c*EE + base;
          #pragma unroll
          for (int d = 0; d < HD; ++d) qv[d] += a * wr[d];
        }
        float m = -INFINITY, l = 0.f, ov[HD];
        #pragma unroll
        for (int d = 0; d < HD; ++d) ov[d] = 0.f;
        for (int k = 0; k < CC; ++k) {
          const float4* kr4 = (const float4*)(s_k + k*HD);
          float s0=0.f,s1=0.f,s2=0.f,s3=0.f;
          #pragma unroll
          for (int i = 0; i < 16; ++i) {
            float4 kk4 = kr4[i];
            s0 += qv[4*i  ]*kk4.x; s1 += qv[4*i+1]*kk4.y;
            s2 += qv[4*i+2]*kk4.z; s3 += qv[4*i+3]*kk4.w;
          }
          float s  = (s0+s1+s2+s3) * 0.125f;
          float mn = fmaxf(m, s);
          float corr = __expf(m - mn);
          float p    = __expf(s - mn);
          l = l*corr + p;
          const float4* vr4 = (const float4*)(s_v + k*HD);
          #pragma unroll
          for (int i = 0; i < 16; ++i) {
            float4 vv4 = vr4[i];
            ov[4*i  ] = ov[4*i  ]*corr + p*vv4.x;
            ov[4*i+1] = ov[4*i+1]*corr + p*vv4.y;
            ov[4*i+2] = ov[4*i+2]*corr + p*vv4.z;
            ov[4*i+3] = ov[4*i+3]*corr + p*vv4.w;
          }
          m = mn;
        }
        float rl = 1.f/l;
        #pragma unroll
        for (int d = 0; d < HD; ++d) ov[d] *= rl;
        for (int c = 0; c < CC; ++c) {
          const float* wr = st_wo + (long)base*CC + c;
          float a0=0.f,a1=0.f,a2=0.f,a3=0.f;
          #pragma unroll
          for (int d = 0; d < HD; d += 4) {
            a0 += ov[d  ]*wr[(long)(d  )*CC]; a1 += ov[d+1]*wr[(long)(d+1)*CC];
            a2 += ov[d+2]*wr[(long)(d+2)*CC]; a3 += ov[d+3]*wr[(long)(d+3)*CC];
          }
          s_comb[c*CPAD + q] += a0+a1+a2+a3;
        }
      }
    }
  }

  {
    float* s_k = s_kv;
    float* s_v = s_kv + TT*HD;
    for (int h = 0; h < HH; ++h) {
      const int base = h*HD;
      __syncthreads();
      {
        const int d = tid & 63, krow = tid >> 6;
        for (int kk = 0; kk < TT/2; ++kk) {
          int k = kk*2 + krow;
          float aK = ts_bk[base + d], aV = ts_bv[base + d];
          for (int c = 0; c < CC; ++c) {
            float a = s_sp[c*TT + k];
            aK += a * ts_wk[(long)c*EE + base + d];
            aV += a * ts_wv[(long)c*EE + base + d];
          }
          s_k[k*HD + d] = aK;
          s_v[k*HD + d] = aV;
        }
      }
      __syncthreads();
      if (tid < CC) {
        const int q = tid;
        float qv[HD];
        #pragma unroll
        for (int d = 0; d < HD; ++d) qv[d] = ts_bq[base + d];
        const float* tr = s_tp + q*TT;
        for (int t = 0; t < TT; ++t) {
          float a = tr[t];
          const float* wr = ts_wq + (long)t*EE + base;
          #pragma unroll
          for (int d = 0; d < HD; ++d) qv[d] += a * wr[d];
        }
        float m = -INFINITY, l = 0.f, ov[HD];
        #pragma unroll
        for (int d = 0; d < HD; ++d) ov[d] = 0.f;
        for (int k = 0; k < TT; ++k) {
          const float4* kr4 = (const float4*)(s_k + k*HD);
          float s0=0.f,s1=0.f,s2=0.f,s3=0.f;
          #pragma unroll
          for (int i = 0; i < 16; ++i) {
            float4 kk4 = kr4[i];
            s0 += qv[4*i  ]*kk4.x; s1 += qv[4*i+1]*kk4.y;
            s2 += qv[4*i+2]*kk4.z; s3 += qv[4*i+3]*kk4.w;
          }
          float s  = (s0+s1+s2+s3) * 0.125f;
          float mn = fmaxf(m, s);
          float corr = __expf(m - mn);
          float p    = __expf(s - mn);
          l = l*corr + p;
          const float4* vr4 = (const float4*)(s_v + k*HD);
          #pragma unroll
          for (int i = 0; i < 16; ++i) {
            float4 vv4 = vr4[i];
            ov[4*i  ] = ov[4*i  ]*corr + p*vv4.x;
            ov[4*i+1] = ov[4*i+1]*corr + p*vv4.y;
            ov[4*i+2] = ov[4*i+2]*corr + p*vv4.z;
            ov[4*i+3] = ov[4*i+3]*corr + p*vv4.w;
          }
          m = mn;
        }
        float rl = 1.f/l;
        #pragma unroll
        for (int d = 0; d < HD; ++d) ov[d] *= rl;
        for (int t = 0; t < TT; ++t) {
          const float* wr = ts_wo + (long)base*TT + t;
          float a0=0.f,a1=0.f,a2=0.f,a3=0.f;
          #pragma unroll
          for (int d = 0; d < HD; d += 4) {
            a0 += ov[d  ]*wr[(long)(d  )*TT]; a1 += ov[d+1]*wr[(long)(d+1)*TT];
            a2 += ov[d+2]*wr[(long)(d+2)*TT]; a3 += ov[d+3]*wr[(long)(d+3)*TT];
          }
          s_comb[q*CPAD + t] += a0+a1+a2+a3;
        }
      }
    }
  }
  __syncthreads();

  if (tid < TT) {
    const int t = tid;
    float mean = 0.f;
    for (int c = 0; c < CC; ++c) mean += s_comb[c*CPAD + t];
    mean *= (1.f/CC);
    float var = 0.f;
    for (int c = 0; c < CC; ++c) { float dv = s_comb[c*CPAD + t] - mean; var += dv*dv; }
    var *= (1.f/CC);
    float rstd = 1.f / sqrtf(var + 1e-5f);
    for (int c = 0; c < CC; ++c) {
      float y = (s_comb[c*CPAD + t] - mean) * rstd * alpha[c] + beta[c];
      s_comb[c*CPAD + t] = y + x[bb + c*TT + t];
    }
  }
  __syncthreads();

  float* s_w = s_kv;
  for (int o = tid; o < TT*TT; o += 128) {
    int f = o / TT, t = o - f*TT;
    s_w[t*TT + f] = fcw[o];
  }
  __syncthreads();

  for (int o = tid; o < CC*TT; o += 128) {
    int c = o / TT, f = o - c*TT;
    const float* cr = s_comb + c*CPAD;
    float a0 = 0.f, a1 = 0.f;
    for (int t = 0; t < TT; t += 2) {
      a0 += cr[t    ] * s_w[(t    )*TT + f];
      a1 += cr[t + 1] * s_w[(t + 1)*TT + f];
    }
    out[bb + o] = tanhf(a0 + a1 + fcb[f]);
  }
}

// ---------------------------------------------------------------- launch
extern "C" void kernel_launch(void* const* d_in, const int* in_sizes, int n_in,
                              void* d_out, int out_size, void* d_ws, size_t ws_size,
                              hipStream_t stream) {
  const float* x     = (const float*)d_in[0];
  const float* adj   = (const float*)d_in[1];
  const float* sadj  = (const float*)d_in[2];
  const float* tmask = (const float*)d_in[3];
  const float* tadj  = (const float*)d_in[4];
  const float* st_wq = (const float*)d_in[5];  const float* st_bq = (const float*)d_in[6];
  const float* st_wk = (const float*)d_in[7];  const float* st_bk = (const float*)d_in[8];
  const float* st_wv = (const float*)d_in[9];  const float* st_bv = (const float*)d_in[10];
  const float* st_wo = (const float*)d_in[11]; const float* st_bo = (const float*)d_in[12];
  const float* ts_wq = (const float*)d_in[13]; const float* ts_bq = (const float*)d_in[14];
  const float* ts_wk = (const float*)d_in[15]; const float* ts_bk = (const float*)d_in[16];
  const float* ts_wv = (const float*)d_in[17]; const float* ts_bv = (const float*)d_in[18];
  const float* ts_wo = (const float*)d_in[19]; const float* ts_bo = (const float*)d_in[20];
  const float* alpha = (const float*)d_in[21]; const float* beta  = (const float*)d_in[22];
  const float* fcw   = (const float*)d_in[23]; const float* fcb   = (const float*)d_in[24];
  float* out = (float*)d_out;

  const int B = in_sizes[0] / (CC*TT);
  const size_t N = (size_t)B * CC * TT;
  const size_t need = N*2 + N*2 + N*4;   // sp bf16 | tp bf16 | comb f32

  if (ws_size >= need) {
    bf16*  sp_g   = (bf16*)d_ws;
    bf16*  tp_g   = sp_g + N;
    float* comb_g = (float*)((char*)d_ws + N*4);
    hipMemsetAsync(comb_g, 0, N*4, stream);
    k_prep<<<B, 256, 0, stream>>>(x, adj, sadj, tmask, tadj, sp_g, tp_g);
    k_attn<<<B*2, 256, 0, stream>>>(sp_g, tp_g,
                                    st_wq, st_bq, st_wk, st_bk, st_wv, st_bv, st_wo,
                                    ts_wq, ts_bq, ts_wk, ts_bk, ts_wv, ts_bv, ts_wo,
                                    comb_g);
    k_epi<<<B, 256, 0, stream>>>(comb_g, x, st_bo, ts_bo, alpha, beta, fcw, fcb, out);
  } else {
    k_fused<<<B, 128, 0, stream>>>(x, adj, sadj, tmask, tadj,
                                   st_wq, st_bq, st_wk, st_bk, st_wv, st_bv, st_wo, st_bo,
                                   ts_wq, ts_bq, ts_wk, ts_bk, ts_wv, ts_bv, ts_wo, ts_bo,
                                   alpha, beta, fcw, fcb, out);
  }
}

// Round 7
// 1985.148 us; speedup vs baseline: 8.7007x; 3.3264x over previous
//
#include <hip/hip_runtime.h>
#include <hip/hip_bf16.h>
#include <math.h>
#include <stdint.h>

typedef __hip_bfloat16 bf16;
typedef __attribute__((ext_vector_type(8))) short short8;
typedef __attribute__((ext_vector_type(4))) float f32x4;

#define CC 66      // channels = J*DIMS
#define TT 100     // time steps
#define JJ 22      // joints
#define HH 8       // heads
#define HD 64      // head dim
#define EE 512     // embed
#define CPAD 101   // comb LDS stride in k_epi / k_fused

__device__ __forceinline__ float b2f(bf16 v){ return __bfloat162float(v); }
__device__ __forceinline__ bf16 f2b(float v){ return __float2bfloat16(v); }
__device__ __forceinline__ short sb(float v){ __hip_bfloat16 h = __float2bfloat16(v); return *(short*)&h; }
__device__ __forceinline__ float fb(short s){ __hip_bfloat16 h; *(short*)&h = s; return __bfloat162float(h); }

// ---------------------------------------------------------------- k_prep
// B blocks x 256: spT = (A@x)^T  [t][c], tp = x@M^T [n][f]  -> ws bf16
__global__ __launch_bounds__(256) void k_prep(
    const float* __restrict__ x, const float* __restrict__ adj,
    const float* __restrict__ sadj, const float* __restrict__ tmask,
    const float* __restrict__ tadj,
    bf16* __restrict__ spT_g, bf16* __restrict__ tp_g)
{
  __shared__ float s_x[CC*TT];
  __shared__ float s_Mt[TT*TT];
  __shared__ float s_A[JJ*JJ];
  __shared__ float s_dis[JJ];
  const int b = blockIdx.x, tid = threadIdx.x;
  const long bb = (long)b * (CC*TT);

  if (tid < JJ) {
    float dsum = 0.f;
    for (int i = 0; i < JJ; ++i) dsum += adj[tid*JJ + i];
    s_dis[tid] = dsum > 0.f ? rsqrtf(dsum) : 0.f;
  }
  for (int o = tid; o < CC*TT; o += 256) s_x[o] = x[bb + o];
  for (int o = tid; o < TT*TT; o += 256) {
    int f = o / TT, t = o - f*TT;
    s_Mt[t*TT + f] = tadj[o] * tmask[o];
  }
  __syncthreads();
  for (int o = tid; o < JJ*JJ; o += 256) {
    int v = o / JJ, j = o - v*JJ;
    s_A[o] = sadj[o] * adj[o] * s_dis[v] * s_dis[j];
  }
  __syncthreads();

  // spT[t][c] = sum_j A[v][j] x[(j*3+dd)][t]
  for (int o = tid; o < CC*TT; o += 256) {
    int t = o / CC, c = o - t*CC, v = c / 3, dd = c - v*3;
    float acc = 0.f;
    for (int j = 0; j < JJ; ++j) acc += s_A[v*JJ + j] * s_x[(j*3 + dd)*TT + t];
    spT_g[bb + o] = f2b(acc);
  }
  // tp[n][f] = sum_t x[n][t] M[f][t]
  for (int o = tid; o < CC*TT; o += 256) {
    int n = o / TT, f = o - n*TT;
    float a0 = 0.f, a1 = 0.f;
    for (int t = 0; t < TT; t += 2) {
      a0 += s_x[n*TT + t    ] * s_Mt[(t    )*TT + f];
      a1 += s_x[n*TT + t + 1] * s_Mt[(t + 1)*TT + f];
    }
    tp_g[bb + o] = f2b(a0 + a1);
  }
}

// ---------------------------------------------------------------- MFMA helpers
// verified layouts (guide §3): A[m=lane&15][k=quad*8+j]; B[n=lane&15][k=quad*8+j];
// D col=lane&15, row=quad*4+reg.
__device__ __forceinline__ void mm_tiles(
    int Mt, int Nt, int kch,
    const short* __restrict__ A, int sA,
    const short* __restrict__ Bm, int sB,
    short* __restrict__ D, int sD,
    const float* __restrict__ bias, float scale,
    int wave, int ln, int qd)
{
  for (int ti = wave; ti < Mt*Nt; ti += 8) {
    int mi = ti / Nt, ni = ti - mi*Nt;
    f32x4 acc = {0.f, 0.f, 0.f, 0.f};
    const short* ap = A  + (mi*16 + ln)*sA + qd*8;
    const short* bp = Bm + (ni*16 + ln)*sB + qd*8;
    for (int kc = 0; kc < kch; ++kc) {
      short8 af = *(const short8*)(ap + kc*32);
      short8 bf = *(const short8*)(bp + kc*32);
      acc = __builtin_amdgcn_mfma_f32_16x16x32_bf16(af, bf, acc, 0, 0, 0);
    }
    int col = ni*16 + ln;
    float bv_ = bias ? bias[col] : 0.f;
    short* dp = D + (mi*16 + qd*4)*sD + col;
    #pragma unroll
    for (int r = 0; r < 4; ++r) dp[r*sD] = sb((acc[r] + bv_) * scale);
  }
}

// stage W^T[d][k] = g[k*EE + base + d] (k<kreal else 0); coalesced on d
__device__ __forceinline__ void stage_wT(
    const float* __restrict__ g, int base, int kreal, int stride,
    short* __restrict__ W, int tid)
{
  for (int o = tid; o < 64*stride; o += 512) {
    int d = o & 63, k = o >> 6;
    float v = (k < kreal) ? g[(long)k*EE + base + d] : 0.f;
    W[d*stride + k] = sb(v);
  }
}

// ---------------------------------------------------------------- k_attn (MFMA)
// grid 2B x 512 threads; block (b, a): a=0 attn1 (q=100 spatial tokens, kv=66
// temporal), a=1 attn2 (q=66, kv=100). Out-proj accumulated across heads in
// VGPRs, one atomicAdd pass into comb_g at the end.
// LDS map (shorts). R6 BUG FIX: VT is 64*136=8704, so Q starts at 48000 (was
// 47360 -> VT rows d>=59 were corrupted by the Q build).
#define oSP 0            // [112][104] spT tokens (t x c)
#define oTP 11648        // [80][136]  tp tokens (n x f)
#define oW  22528        // [64][136]  weight^T staging (wk/wv/wq)
#define oK  31232        // [112][72]  K [kt][d]; reused as woT [c|t'][d]
#define oVT 39296        // [64][136]  V^T [d][kt]
#define oQ  48000        // [112][72]  Q [q][d]; reused as O [q][d]
#define oP  56064        // [112][104] S/P [q][kt]  (a=1: [80][136])
#define SMEM_ELE 67712   // total shorts = 135424 B

__global__ __launch_bounds__(512) void k_attn(
    const bf16* __restrict__ spT_g, const bf16* __restrict__ tp_g,
    const float* __restrict__ st_wq, const float* __restrict__ st_bq,
    const float* __restrict__ st_wk, const float* __restrict__ st_wv,
    const float* __restrict__ st_bv, const float* __restrict__ st_wo,
    const float* __restrict__ ts_wq, const float* __restrict__ ts_bq,
    const float* __restrict__ ts_wk, const float* __restrict__ ts_wv,
    const float* __restrict__ ts_bv, const float* __restrict__ ts_wo,
    float* __restrict__ comb_g)
{
  __shared__ short smem[SMEM_ELE];
  const int bid = blockIdx.x, tid = threadIdx.x;
  const int b = bid >> 1, a = bid & 1;
  const long bb = (long)b * (CC*TT);
  const int wave = tid >> 6, lane = tid & 63, ln = lane & 15, qd = lane >> 4;

  const float *wq, *wk, *wv, *wo, *bq, *bv;
  int qrows, krows, qdim, kdim;
  if (a == 0) { wq=st_wq; bq=st_bq; wk=st_wk; wv=st_wv; bv=st_bv; wo=st_wo;
                qrows=TT; krows=CC; qdim=CC; kdim=TT; }
  else        { wq=ts_wq; bq=ts_bq; wk=ts_wk; wv=ts_wv; bv=ts_bv; wo=ts_wo;
                qrows=CC; krows=TT; qdim=TT; kdim=CC; }
  const int Mq  = (qrows + 15) >> 4;   // 7 / 5 query-token tiles
  const int Mk  = (krows + 15) >> 4;   // 5 / 7 kv-token tiles
  const int qch = (qdim + 31) >> 5;    // 3 / 4 K-chunks for Q build
  const int kch = (kdim + 31) >> 5;    // 4 / 3 K-chunks for K/V build
  const int pch = (krows + 31) >> 5;   // 3 / 4 K-chunks for PV
  const int sAq = a ? 136 : 104;       // query-token stride
  const int sAk = a ? 104 : 136;       // kv-token stride (also wk/wv^T stride)
  const int sP  = sAq;                 // S/P stride

  short* SPm = smem + oSP;  short* TPm = smem + oTP;
  short* Wm  = smem + oW;   short* Km  = smem + oK;
  short* VTm = smem + oVT;  short* Qm  = smem + oQ;
  short* Pm  = smem + oP;
  short* Aq = a ? TPm : SPm;
  short* Ak = a ? SPm : TPm;

  // ---- stage tokens (zero-padded) + zero P/VT pads ----
  {
    const short* sp = (const short*)(spT_g + bb);
    const short* tp = (const short*)(tp_g + bb);
    for (int o = tid; o < 112*104; o += 512) {
      int r = o / 104, c = o - r*104;
      SPm[o] = (r < TT && c < CC) ? sp[r*CC + c] : (short)0;
    }
    for (int o = tid; o < 80*136; o += 512) {
      int r = o / 136, c = o - r*136;
      TPm[o] = (r < CC && c < TT) ? tp[r*TT + c] : (short)0;
    }
    for (int o = tid; o < 112*104; o += 512) Pm[o] = 0;
    for (int o = tid; o < 64*136;  o += 512) VTm[o] = 0;
  }
  __syncthreads();

  f32x4 accO[5];
  {
    f32x4 z = {0.f, 0.f, 0.f, 0.f};
    #pragma unroll
    for (int i = 0; i < 5; ++i) accO[i] = z;
  }

  for (int h = 0; h < HH; ++h) {
    const int base = h*HD;
    // K = kv_tokens @ wk (bias dropped: softmax shift-invariant)
    stage_wT(wk, base, kdim, sAk, Wm, tid);
    __syncthreads();
    mm_tiles(Mk, 4, kch, Ak, sAk, Wm, sAk, Km, 72, nullptr, 1.f, wave, ln, qd);
    __syncthreads();
    // V^T = wv^T @ kv_tokens^T  (bias folded at PV epilogue)
    stage_wT(wv, base, kdim, sAk, Wm, tid);
    __syncthreads();
    mm_tiles(4, Mk, kch, Wm, sAk, Ak, sAk, VTm, 136, nullptr, 1.f, wave, ln, qd);
    __syncthreads();
    // Q = q_tokens @ wq + bq
    stage_wT(wq, base, qdim, sAq, Wm, tid);
    __syncthreads();
    mm_tiles(Mq, 4, qch, Aq, sAq, Wm, sAq, Qm, 72, bq + base, 1.f, wave, ln, qd);
    __syncthreads();
    // S = Q @ K^T * 1/8
    mm_tiles(Mq, Mk, 2, Qm, 72, Km, 72, Pm, sP, nullptr, 0.125f, wave, ln, qd);
    __syncthreads();
    // softmax rows (single bf16 rounding: recompute exp in pass 2)
    if (tid < qrows) {
      short* pr = Pm + tid*sP;
      float mx = -INFINITY;
      for (int j = 0; j < krows; ++j) mx = fmaxf(mx, fb(pr[j]));
      float sum = 0.f;
      for (int j = 0; j < krows; ++j) sum += __expf(fb(pr[j]) - mx);
      float rs = 1.f / sum;
      for (int j = 0; j < krows; ++j) pr[j] = sb(__expf(fb(pr[j]) - mx) * rs);
    }
    {  // stage woT into Km (K dead after S)
      const int worows = Mk*16;
      for (int o = tid; o < worows*64; o += 512) {
        int r = o % worows, d = o / worows;
        float v = (r < krows) ? wo[(long)(base + d)*krows + r] : 0.f;
        Km[r*72 + d] = sb(v);
      }
    }
    __syncthreads();
    // O = P @ V + bv   (into Qm; Q dead after S)
    mm_tiles(Mq, 4, pch, Pm, sP, VTm, 136, Qm, 72, bv + base, 1.f, wave, ln, qd);
    __syncthreads();
    // out += O @ wo  (persistent VGPR acc across heads)
    {
      int idx = 0;
      for (int ti = wave; ti < Mq*Mk; ti += 8, ++idx) {
        int mi = ti / Mk, ni = ti - mi*Mk;
        const short* ap = Qm + (mi*16 + ln)*72 + qd*8;
        const short* bp = Km + (ni*16 + ln)*72 + qd*8;
        f32x4 acc = accO[idx];
        acc = __builtin_amdgcn_mfma_f32_16x16x32_bf16(*(const short8*)ap,
                                                      *(const short8*)bp, acc, 0,0,0);
        acc = __builtin_amdgcn_mfma_f32_16x16x32_bf16(*(const short8*)(ap+32),
                                                      *(const short8*)(bp+32), acc, 0,0,0);
        accO[idx] = acc;
      }
    }
    // next head's stage_wT(wk) only touches Wm (disjoint from Qm/Km) — the
    // following barrier orders this head's reads vs next K-build writes.
  }

  // ---- write accumulated out-proj: comb[c][t] ----
  {
    int idx = 0;
    for (int ti = wave; ti < Mq*Mk; ti += 8, ++idx) {
      int mi = ti / Mk, ni = ti - mi*Mk;
      int col = ni*16 + ln;
      #pragma unroll
      for (int r = 0; r < 4; ++r) {
        int row = mi*16 + qd*4 + r;
        if (row < qrows && col < krows) {
          long off = a ? ((long)row*TT + col) : ((long)col*TT + row);
          atomicAdd(&comb_g[bb + off], accO[idx][r]);
        }
      }
    }
  }
}

// ---------------------------------------------------------------- k_epi
__global__ __launch_bounds__(256) void k_epi(
    const float* __restrict__ comb_g, const float* __restrict__ x,
    const float* __restrict__ st_bo, const float* __restrict__ ts_bo,
    const float* __restrict__ alpha, const float* __restrict__ beta,
    const float* __restrict__ fcw, const float* __restrict__ fcb,
    float* __restrict__ out)
{
  __shared__ float s_cb[CC*CPAD];
  __shared__ float s_w[TT*TT];
  const int b = blockIdx.x, tid = threadIdx.x;
  const long bb = (long)b * (CC*TT);

  for (int o = tid; o < CC*TT; o += 256) {
    int c = o / TT, t = o - c*TT;
    s_cb[c*CPAD + t] = comb_g[bb + o] + st_bo[c] + ts_bo[t];
  }
  for (int o = tid; o < TT*TT; o += 256) {
    int f = o / TT, t = o - f*TT;
    s_w[t*TT + f] = fcw[o];
  }
  __syncthreads();
  if (tid < TT) {
    const int t = tid;
    float mean = 0.f;
    for (int c = 0; c < CC; ++c) mean += s_cb[c*CPAD + t];
    mean *= (1.f/CC);
    float var = 0.f;
    for (int c = 0; c < CC; ++c) { float dv = s_cb[c*CPAD + t] - mean; var += dv*dv; }
    var *= (1.f/CC);
    float rstd = 1.f / sqrtf(var + 1e-5f);
    for (int c = 0; c < CC; ++c) {
      float y = (s_cb[c*CPAD + t] - mean) * rstd * alpha[c] + beta[c];
      s_cb[c*CPAD + t] = y + x[bb + c*TT + t];
    }
  }
  __syncthreads();
  for (int o = tid; o < CC*TT; o += 256) {
    int c = o / TT, f = o - c*TT;
    const float* cr = s_cb + c*CPAD;
    float a0 = 0.f, a1 = 0.f;
    for (int t = 0; t < TT; t += 2) {
      a0 += cr[t    ] * s_w[(t    )*TT + f];
      a1 += cr[t + 1] * s_w[(t + 1)*TT + f];
    }
    out[bb + o] = tanhf(a0 + a1 + fcb[f]);
  }
}

// ---------------------------------------------------------------- R4 fallback
__global__ __launch_bounds__(128) void k_fused(
    const float* __restrict__ x, const float* __restrict__ adj,
    const float* __restrict__ sadj, const float* __restrict__ tmask,
    const float* __restrict__ tadj,
    const float* __restrict__ st_wq, const float* __restrict__ st_bq,
    const float* __restrict__ st_wk, const float* __restrict__ st_bk,
    const float* __restrict__ st_wv, const float* __restrict__ st_bv,
    const float* __restrict__ st_wo, const float* __restrict__ st_bo,
    const float* __restrict__ ts_wq, const float* __restrict__ ts_bq,
    const float* __restrict__ ts_wk, const float* __restrict__ ts_bk,
    const float* __restrict__ ts_wv, const float* __restrict__ ts_bv,
    const float* __restrict__ ts_wo, const float* __restrict__ ts_bo,
    const float* __restrict__ alpha, const float* __restrict__ beta,
    const float* __restrict__ fcw, const float* __restrict__ fcb,
    float* __restrict__ out)
{
  __shared__ float s_sp[CC*TT];
  __shared__ float s_tp[CC*TT];
  __shared__ __align__(16) float s_kv[2*TT*HD];
  __shared__ float s_comb[CC*CPAD];
  __shared__ float s_A[JJ*JJ];
  __shared__ float s_dis[JJ];

  const int b = blockIdx.x, tid = threadIdx.x;
  const long bb = (long)b * (CC*TT);
  float* s_xs = s_comb;
  float* s_Mt = s_kv;

  if (tid < JJ) {
    float dsum = 0.f;
    for (int i = 0; i < JJ; ++i) dsum += adj[tid*JJ + i];
    s_dis[tid] = dsum > 0.f ? rsqrtf(dsum) : 0.f;
  }
  for (int o = tid; o < CC*TT; o += 128) s_xs[o] = x[bb + o];
  for (int o = tid; o < TT*TT; o += 128) {
    int f = o / TT, t = o - f*TT;
    s_Mt[t*TT + f] = tadj[o] * tmask[o];
  }
  __syncthreads();
  for (int o = tid; o < JJ*JJ; o += 128) {
    int v = o / JJ, j = o - v*JJ;
    s_A[o] = sadj[o] * adj[o] * s_dis[v] * s_dis[j];
  }
  __syncthreads();

  for (int o = tid; o < CC*TT; o += 128) {
    int c = o / TT, t = o - c*TT, v = c / 3, dd = c - v*3;
    float acc = 0.f;
    for (int j = 0; j < JJ; ++j) acc += s_A[v*JJ + j] * s_xs[(j*3 + dd)*TT + t];
    s_sp[o] = acc;
  }
  for (int o = tid; o < CC*TT; o += 128) {
    int n = o / TT, f = o - n*TT;
    float a0 = 0.f, a1 = 0.f;
    for (int t = 0; t < TT; t += 2) {
      a0 += s_xs[n*TT + t    ] * s_Mt[(t    )*TT + f];
      a1 += s_xs[n*TT + t + 1] * s_Mt[(t + 1)*TT + f];
    }
    s_tp[o] = a0 + a1;
  }
  __syncthreads();

  for (int o = tid; o < CC*TT; o += 128) {
    int c = o / TT, t = o - c*TT;
    s_comb[c*CPAD + t] = st_bo[c] + ts_bo[t];
  }

  {
    float* s_k = s_kv;
    float* s_v = s_kv + TT*HD;
    for (int h = 0; h < HH; ++h) {
      const int base = h*HD;
      __syncthreads();
      {
        const int d = tid & 63, krow = tid >> 6;
        for (int kk = 0; kk < CC/2; ++kk) {
          int k = kk*2 + krow;
          float aK = st_bk[base + d], aV = st_bv[base + d];
          const float* tr = s_tp + k*TT;
          for (int t = 0; t < TT; ++t) {
            float a = tr[t];
            aK += a * st_wk[(long)t*EE + base + d];
            aV += a * st_wv[(long)t*EE + base + d];
          }
          s_k[k*HD + d] = aK;
          s_v[k*HD + d] = aV;
        }
      }
      __syncthreads();
      if (tid < TT) {
        const int q = tid;
        float qv[HD];
        #pragma unroll
        for (int d = 0; d < HD; ++d) qv[d] = st_bq[base + d];
        for (int c = 0; c < CC; ++c) {
          float a = s_sp[c*TT + q];
          const float* wr = st_wq + (long)c*EE + base;
          #pragma unroll
          for (int d = 0; d < HD; ++d) qv[d] += a * wr[d];
        }
        float m = -INFINITY, l = 0.f, ov[HD];
        #pragma unroll
        for (int d = 0; d < HD; ++d) ov[d] = 0.f;
        for (int k = 0; k < CC; ++k) {
          const float4* kr4 = (const float4*)(s_k + k*HD);
          float s0=0.f,s1=0.f,s2=0.f,s3=0.f;
          #pragma unroll
          for (int i = 0; i < 16; ++i) {
            float4 kk4 = kr4[i];
            s0 += qv[4*i  ]*kk4.x; s1 += qv[4*i+1]*kk4.y;
            s2 += qv[4*i+2]*kk4.z; s3 += qv[4*i+3]*kk4.w;
          }
          float s  = (s0+s1+s2+s3) * 0.125f;
          float mn = fmaxf(m, s);
          float corr = __expf(m - mn);
          float p    = __expf(s - mn);
          l = l*corr + p;
          const float4* vr4 = (const float4*)(s_v + k*HD);
          #pragma unroll
          for (int i = 0; i < 16; ++i) {
            float4 vv4 = vr4[i];
            ov[4*i  ] = ov[4*i  ]*corr + p*vv4.x;
            ov[4*i+1] = ov[4*i+1]*corr + p*vv4.y;
            ov[4*i+2] = ov[4*i+2]*corr + p*vv4.z;
            ov[4*i+3] = ov[4*i+3]*corr + p*vv4.w;
          }
          m = mn;
        }
        float rl = 1.f/l;
        #pragma unroll
        for (int d = 0; d < HD; ++d) ov[d] *= rl;
        for (int c = 0; c < CC; ++c) {
          const float* wr = st_wo + (long)base*CC + c;
          float a0=0.f,a1=0.f,a2=0.f,a3=0.f;
          #pragma unroll
          for (int d = 0; d < HD; d += 4) {
            a0 += ov[d  ]*wr[(long)(d  )*CC]; a1 += ov[d+1]*wr[(long)(d+1)*CC];
            a2 += ov[d+2]*wr[(long)(d+2)*CC]; a3 += ov[d+3]*wr[(long)(d+3)*CC];
          }
          s_comb[c*CPAD + q] += a0+a1+a2+a3;
        }
      }
    }
  }

  {
    float* s_k = s_kv;
    float* s_v = s_kv + TT*HD;
    for (int h = 0; h < HH; ++h) {
      const int base = h*HD;
      __syncthreads();
      {
        const int d = tid & 63, krow = tid >> 6;
        for (int kk = 0; kk < TT/2; ++kk) {
          int k = kk*2 + krow;
          float aK = ts_bk[base + d], aV = ts_bv[base + d];
          for (int c = 0; c < CC; ++c) {
            float a = s_sp[c*TT + k];
            aK += a * ts_wk[(long)c*EE + base + d];
            aV += a * ts_wv[(long)c*EE + base + d];
          }
          s_k[k*HD + d] = aK;
          s_v[k*HD + d] = aV;
        }
      }
      __syncthreads();
      if (tid < CC) {
        const int q = tid;
        float qv[HD];
        #pragma unroll
        for (int d = 0; d < HD; ++d) qv[d] = ts_bq[base + d];
        const float* tr = s_tp + q*TT;
        for (int t = 0; t < TT; ++t) {
          float a = tr[t];
          const float* wr = ts_wq + (long)t*EE + base;
          #pragma unroll
          for (int d = 0; d < HD; ++d) qv[d] += a * wr[d];
        }
        float m = -INFINITY, l = 0.f, ov[HD];
        #pragma unroll
        for (int d = 0; d < HD; ++d) ov[d] = 0.f;
        for (int k = 0; k < TT; ++k) {
          const float4* kr4 = (const float4*)(s_k + k*HD);
          float s0=0.f,s1=0.f,s2=0.f,s3=0.f;
          #pragma unroll
          for (int i = 0; i < 16; ++i) {
            float4 kk4 = kr4[i];
            s0 += qv[4*i  ]*kk4.x; s1 += qv[4*i+1]*kk4.y;
            s2 += qv[4*i+2]*kk4.z; s3 += qv[4*i+3]*kk4.w;
          }
          float s  = (s0+s1+s2+s3) * 0.125f;
          float mn = fmaxf(m, s);
          float corr = __expf(m - mn);
          float p    = __expf(s - mn);
          l = l*corr + p;
          const float4* vr4 = (const float4*)(s_v + k*HD);
          #pragma unroll
          for (int i = 0; i < 16; ++i) {
            float4 vv4 = vr4[i];
            ov[4*i  ] = ov[4*i  ]*corr + p*vv4.x;
            ov[4*i+1] = ov[4*i+1]*corr + p*vv4.y;
            ov[4*i+2] = ov[4*i+2]*corr + p*vv4.z;
            ov[4*i+3] = ov[4*i+3]*corr + p*vv4.w;
          }
          m = mn;
        }
        float rl = 1.f/l;
        #pragma unroll
        for (int d = 0; d < HD; ++d) ov[d] *= rl;
        for (int t = 0; t < TT; ++t) {
          const float* wr = ts_wo + (long)base*TT + t;
          float a0=0.f,a1=0.f,a2=0.f,a3=0.f;
          #pragma unroll
          for (int d = 0; d < HD; d += 4) {
            a0 += ov[d  ]*wr[(long)(d  )*TT]; a1 += ov[d+1]*wr[(long)(d+1)*TT];
            a2 += ov[d+2]*wr[(long)(d+2)*TT]; a3 += ov[d+3]*wr[(long)(d+3)*TT];
          }
          s_comb[q*CPAD + t] += a0+a1+a2+a3;
        }
      }
    }
  }
  __syncthreads();

  if (tid < TT) {
    const int t = tid;
    float mean = 0.f;
    for (int c = 0; c < CC; ++c) mean += s_comb[c*CPAD + t];
    mean *= (1.f/CC);
    float var = 0.f;
    for (int c = 0; c < CC; ++c) { float dv = s_comb[c*CPAD + t] - mean; var += dv*dv; }
    var *= (1.f/CC);
    float rstd = 1.f / sqrtf(var + 1e-5f);
    for (int c = 0; c < CC; ++c) {
      float y = (s_comb[c*CPAD + t] - mean) * rstd * alpha[c] + beta[c];
      s_comb[c*CPAD + t] = y + x[bb + c*TT + t];
    }
  }
  __syncthreads();

  float* s_w = s_kv;
  for (int o = tid; o < TT*TT; o += 128) {
    int f = o / TT, t = o - f*TT;
    s_w[t*TT + f] = fcw[o];
  }
  __syncthreads();

  for (int o = tid; o < CC*TT; o += 128) {
    int c = o / TT, f = o - c*TT;
    const float* cr = s_comb + c*CPAD;
    float a0 = 0.f, a1 = 0.f;
    for (int t = 0; t < TT; t += 2) {
      a0 += cr[t    ] * s_w[(t    )*TT + f];
      a1 += cr[t + 1] * s_w[(t + 1)*TT + f];
    }
    out[bb + o] = tanhf(a0 + a1 + fcb[f]);
  }
}

// ---------------------------------------------------------------- launch
extern "C" void kernel_launch(void* const* d_in, const int* in_sizes, int n_in,
                              void* d_out, int out_size, void* d_ws, size_t ws_size,
                              hipStream_t stream) {
  const float* x     = (const float*)d_in[0];
  const float* adj   = (const float*)d_in[1];
  const float* sadj  = (const float*)d_in[2];
  const float* tmask = (const float*)d_in[3];
  const float* tadj  = (const float*)d_in[4];
  const float* st_wq = (const float*)d_in[5];  const float* st_bq = (const float*)d_in[6];
  const float* st_wk = (const float*)d_in[7];  const float* st_bk = (const float*)d_in[8];
  const float* st_wv = (const float*)d_in[9];  const float* st_bv = (const float*)d_in[10];
  const float* st_wo = (const float*)d_in[11]; const float* st_bo = (const float*)d_in[12];
  const float* ts_wq = (const float*)d_in[13]; const float* ts_bq = (const float*)d_in[14];
  const float* ts_wk = (const float*)d_in[15]; const float* ts_bk = (const float*)d_in[16];
  const float* ts_wv = (const float*)d_in[17]; const float* ts_bv = (const float*)d_in[18];
  const float* ts_wo = (const float*)d_in[19]; const float* ts_bo = (const float*)d_in[20];
  const float* alpha = (const float*)d_in[21]; const float* beta  = (const float*)d_in[22];
  const float* fcw   = (const float*)d_in[23]; const float* fcb   = (const float*)d_in[24];
  float* out = (float*)d_out;

  const int B = in_sizes[0] / (CC*TT);
  const size_t N = (size_t)B * CC * TT;
  const size_t need = N*2 + N*2 + N*4;   // spT bf16 | tp bf16 | comb f32

  if (ws_size >= need) {
    bf16*  spT_g  = (bf16*)d_ws;
    bf16*  tp_g   = spT_g + N;
    float* comb_g = (float*)((char*)d_ws + N*4);
    hipMemsetAsync(comb_g, 0, N*4, stream);
    k_prep<<<B, 256, 0, stream>>>(x, adj, sadj, tmask, tadj, spT_g, tp_g);
    k_attn<<<B*2, 512, 0, stream>>>(spT_g, tp_g,
                                    st_wq, st_bq, st_wk, st_wv, st_bv, st_wo,
                                    ts_wq, ts_bq, ts_wk, ts_wv, ts_bv, ts_wo,
                                    comb_g);
    k_epi<<<B, 256, 0, stream>>>(comb_g, x, st_bo, ts_bo, alpha, beta, fcw, fcb, out);
  } else {
    k_fused<<<B, 128, 0, stream>>>(x, adj, sadj, tmask, tadj,
                                   st_wq, st_bq, st_wk, st_bk, st_wv, st_bv, st_wo, st_bo,
                                   ts_wq, ts_bq, ts_wk, ts_bk, ts_wv, ts_bv, ts_wo, ts_bo,
                                   alpha, beta, fcw, fcb, out);
  }
}

// Round 8
// 1469.836 us; speedup vs baseline: 11.7511x; 1.3506x over previous
//
#include <hip/hip_runtime.h>
#include <hip/hip_bf16.h>
#include <math.h>
#include <stdint.h>

typedef __hip_bfloat16 bf16;
typedef __attribute__((ext_vector_type(8))) short short8;
typedef __attribute__((ext_vector_type(4))) short short4v;
typedef __attribute__((ext_vector_type(4))) float f32x4;

#define CC 66      // channels = J*DIMS
#define TT 100     // time steps
#define JJ 22      // joints
#define HH 8       // heads
#define HD 64      // head dim
#define EE 512     // embed
#define CPAD 101   // comb LDS stride in k_epi / k_fused

// padded token layouts in ws (zero-padded so MFMA K-chunks read clean zeros)
#define SPT_R 112  // spT rows (>=100, mult of 16)
#define SPT_S 96   // spT stride (>=66, mult of 32 for k-chunks)
#define TP_R 80    // tp rows (>=66)
#define TP_S 128   // tp stride (>=100)

// weight section offsets (bf16 elements) inside ws
#define W_STWK 0                    // [512][128]
#define W_STWV 65536                // [512][128]
#define W_STWQ 131072               // [512][96]
#define W_STWO 180224               // [80][512]
#define W_TSWK 221184               // [512][96]
#define W_TSWV 270336               // [512][96]
#define W_TSWQ 319488               // [512][128]
#define W_TSWO 385024               // [112][512]
#define W_TOTAL 442368

__device__ __forceinline__ float b2f(bf16 v){ return __bfloat162float(v); }
__device__ __forceinline__ bf16 f2b(float v){ return __float2bfloat16(v); }
__device__ __forceinline__ short sb(float v){ __hip_bfloat16 h = __float2bfloat16(v); return *(short*)&h; }
__device__ __forceinline__ float fb(short s){ __hip_bfloat16 h; *(short*)&h = s; return __bfloat162float(h); }

// ---------------------------------------------------------------- k_tr
// generic zero-padded transpose: dst[j][i] = (j<Csrc && i<Rsrc) ? src[i][j] : 0
__global__ void k_tr(const float* __restrict__ src, bf16* __restrict__ dst,
                     int Rsrc, int Csrc, int JP, int IP)
{
  int o = blockIdx.x*256 + threadIdx.x;
  if (o >= JP*IP) return;
  int j = o / IP, i = o - j*IP;
  float v = (j < Csrc && i < Rsrc) ? src[(long)i*Csrc + j] : 0.f;
  dst[o] = f2b(v);
}

// ---------------------------------------------------------------- k_prep
// B blocks x 256: spT_pad [112][96] = (A@x)^T, tp_pad [80][128] = x@M^T
__global__ __launch_bounds__(256) void k_prep(
    const float* __restrict__ x, const float* __restrict__ adj,
    const float* __restrict__ sadj, const float* __restrict__ tmask,
    const float* __restrict__ tadj,
    bf16* __restrict__ spT_all, bf16* __restrict__ tp_all)
{
  __shared__ float s_x[CC*TT];
  __shared__ float s_Mt[TT*TT];
  __shared__ float s_A[JJ*JJ];
  __shared__ float s_dis[JJ];
  const int b = blockIdx.x, tid = threadIdx.x;
  const long bb = (long)b * (CC*TT);

  if (tid < JJ) {
    float dsum = 0.f;
    for (int i = 0; i < JJ; ++i) dsum += adj[tid*JJ + i];
    s_dis[tid] = dsum > 0.f ? rsqrtf(dsum) : 0.f;
  }
  for (int o = tid; o < CC*TT; o += 256) s_x[o] = x[bb + o];
  for (int o = tid; o < TT*TT; o += 256) {
    int f = o / TT, t = o - f*TT;
    s_Mt[t*TT + f] = tadj[o] * tmask[o];
  }
  __syncthreads();
  for (int o = tid; o < JJ*JJ; o += 256) {
    int v = o / JJ, j = o - v*JJ;
    s_A[o] = sadj[o] * adj[o] * s_dis[v] * s_dis[j];
  }
  __syncthreads();

  bf16* spT = spT_all + (long)b * (SPT_R*SPT_S);
  bf16* tp  = tp_all  + (long)b * (TP_R*TP_S);

  // spT[t][c] = sum_j A[v][j] x[(j*3+dd)][t], zero-padded
  for (int o = tid; o < SPT_R*SPT_S; o += 256) {
    int t = o / SPT_S, c = o - t*SPT_S;
    float acc = 0.f;
    if (t < TT && c < CC) {
      int v = c / 3, dd = c - v*3;
      for (int j = 0; j < JJ; ++j) acc += s_A[v*JJ + j] * s_x[(j*3 + dd)*TT + t];
    }
    spT[o] = f2b(acc);
  }
  // tp[n][f] = sum_t x[n][t] M[f][t], zero-padded
  for (int o = tid; o < TP_R*TP_S; o += 256) {
    int n = o / TP_S, f = o - n*TP_S;
    float acc = 0.f;
    if (n < CC && f < TT) {
      float a0 = 0.f, a1 = 0.f;
      for (int t = 0; t < TT; t += 2) {
        a0 += s_x[n*TT + t    ] * s_Mt[(t    )*TT + f];
        a1 += s_x[n*TT + t + 1] * s_Mt[(t + 1)*TT + f];
      }
      acc = a0 + a1;
    }
    tp[o] = f2b(acc);
  }
}

// ---------------------------------------------------------------- MFMA helper
// A[m=lane&15][k=quad*8+j]; B[n=lane&15][k=quad*8+j]; D col=lane&15,row=quad*4+reg.
// A/B pointers may be LDS or global (inlined; compiler infers address space).
__device__ __forceinline__ void mm_tiles(
    int Mt, int Nt, int kch,
    const short* __restrict__ A, int sA,
    const short* __restrict__ Bm, int sB,
    short* __restrict__ D, int sD,
    const float* __restrict__ bias, float scale,
    int wave, int ln, int qd)
{
  for (int ti = wave; ti < Mt*Nt; ti += 8) {
    int mi = ti / Nt, ni = ti - mi*Nt;
    f32x4 acc = {0.f, 0.f, 0.f, 0.f};
    const short* ap = A  + (long)(mi*16 + ln)*sA + qd*8;
    const short* bp = Bm + (long)(ni*16 + ln)*sB + qd*8;
    for (int kc = 0; kc < kch; ++kc) {
      short8 af = *(const short8*)(ap + kc*32);
      short8 bf = *(const short8*)(bp + kc*32);
      acc = __builtin_amdgcn_mfma_f32_16x16x32_bf16(af, bf, acc, 0, 0, 0);
    }
    int col = ni*16 + ln;
    float bv_ = bias ? bias[col] : 0.f;
    short* dp = D + (mi*16 + qd*4)*sD + col;
    #pragma unroll
    for (int r = 0; r < 4; ++r) dp[r*sD] = sb((acc[r] + bv_) * scale);
  }
}

// ---------------------------------------------------------------- k_attn (MFMA)
// grid 2B x 512; block (b,a). Weights pre-transposed in ws (global B-operands);
// tokens zero-padded in ws (global A-operands). LDS only for K/VT/Q(O)/P.
// 78.2 KB LDS -> 2 blocks/CU. 5 barriers/head.
__global__ __launch_bounds__(512) void k_attn(
    const bf16* __restrict__ spT_all, const bf16* __restrict__ tp_all,
    const bf16* __restrict__ wsec,
    const float* __restrict__ st_bq, const float* __restrict__ st_bv,
    const float* __restrict__ ts_bq, const float* __restrict__ ts_bv,
    float* __restrict__ comb_g)
{
  __shared__ __align__(16) short Km [SPT_R*72];   // K [kt][d]        8064
  __shared__ __align__(16) short VTm[64*136];     // V^T [d][kt]      8704
  __shared__ __align__(16) short Qm [SPT_R*72];   // Q then O [q][d]  8064
  __shared__ __align__(16) short Pm [SPT_R*136];  // S/P [q][kt]     15232
  const int bid = blockIdx.x, tid = threadIdx.x;
  const int b = bid >> 1, a = bid & 1;
  const long bb = (long)b * (CC*TT);
  const int wave = tid >> 6, lane = tid & 63, ln = lane & 15, qd = lane >> 4;

  const short *Aq, *Ak, *wqT, *wkT, *wvT, *woT;
  const float *bq, *bv;
  int qrows, krows, Mq, Mk, qch, kch, pch, sAq, sAk;
  if (a == 0) {        // attn1: q = spatial tokens (100), kv = temporal (66)
    Aq = (const short*)(spT_all + (long)b*SPT_R*SPT_S); sAq = SPT_S;
    Ak = (const short*)(tp_all  + (long)b*TP_R*TP_S);   sAk = TP_S;
    wqT = (const short*)(wsec + W_STWQ); wkT = (const short*)(wsec + W_STWK);
    wvT = (const short*)(wsec + W_STWV); woT = (const short*)(wsec + W_STWO);
    bq = st_bq; bv = st_bv;
    qrows = TT; krows = CC; Mq = 7; Mk = 5; qch = 3; kch = 4; pch = 3;
  } else {             // attn2: q = temporal tokens (66), kv = spatial (100)
    Aq = (const short*)(tp_all  + (long)b*TP_R*TP_S);   sAq = TP_S;
    Ak = (const short*)(spT_all + (long)b*SPT_R*SPT_S); sAk = SPT_S;
    wqT = (const short*)(wsec + W_TSWQ); wkT = (const short*)(wsec + W_TSWK);
    wvT = (const short*)(wsec + W_TSWV); woT = (const short*)(wsec + W_TSWO);
    bq = ts_bq; bv = ts_bv;
    qrows = CC; krows = TT; Mq = 5; Mk = 7; qch = 4; kch = 3; pch = 4;
  }

  // zero-init P and VT pads (correctness depends on pad columns being zero)
  for (int o = tid; o < SPT_R*136; o += 512) Pm[o] = 0;
  for (int o = tid; o < 64*136;   o += 512) VTm[o] = 0;
  __syncthreads();

  f32x4 accO[5];
  { f32x4 z = {0.f,0.f,0.f,0.f}; for (int i = 0; i < 5; ++i) accO[i] = z; }

  for (int h = 0; h < HH; ++h) {
    const int base = h*HD;
    // builds: all operands global, disjoint LDS outputs -> no inner barriers
    mm_tiles(Mk, 4, kch, Ak, sAk, wkT + (long)base*sAk, sAk, Km, 72,
             nullptr, 1.f, wave, ln, qd);                       // K
    mm_tiles(4, Mk, kch, wvT + (long)base*sAk, sAk, Ak, sAk, VTm, 136,
             nullptr, 1.f, wave, ln, qd);                       // V^T
    mm_tiles(Mq, 4, qch, Aq, sAq, wqT + (long)base*sAq, sAq, Qm, 72,
             bq + base, 1.f, wave, ln, qd);                     // Q (+bq)
    __syncthreads();
    // S = Q @ K^T * 1/8
    mm_tiles(Mq, Mk, 2, Qm, 72, Km, 72, Pm, 136, nullptr, 0.125f, wave, ln, qd);
    __syncthreads();
    // softmax per row (vectorized short4)
    if (tid < qrows) {
      short* pr = Pm + tid*136;
      const int full = krows >> 2, rem = krows & 3;
      float mx = -INFINITY;
      for (int j4 = 0; j4 < full; ++j4) {
        short4v v = ((const short4v*)pr)[j4];
        mx = fmaxf(mx, fmaxf(fmaxf(fb(v.x), fb(v.y)), fmaxf(fb(v.z), fb(v.w))));
      }
      for (int j = full*4; j < full*4 + rem; ++j) mx = fmaxf(mx, fb(pr[j]));
      float sum = 0.f;
      for (int j4 = 0; j4 < full; ++j4) {
        short4v v = ((const short4v*)pr)[j4];
        sum += __expf(fb(v.x)-mx) + __expf(fb(v.y)-mx)
             + __expf(fb(v.z)-mx) + __expf(fb(v.w)-mx);
      }
      for (int j = full*4; j < full*4 + rem; ++j) sum += __expf(fb(pr[j]) - mx);
      float rs = 1.f / sum;
      for (int j4 = 0; j4 < full; ++j4) {
        short4v v = ((const short4v*)pr)[j4];
        short4v w;
        w.x = sb(__expf(fb(v.x)-mx)*rs); w.y = sb(__expf(fb(v.y)-mx)*rs);
        w.z = sb(__expf(fb(v.z)-mx)*rs); w.w = sb(__expf(fb(v.w)-mx)*rs);
        ((short4v*)pr)[j4] = w;
      }
      for (int j = full*4; j < full*4 + rem; ++j)
        pr[j] = sb(__expf(fb(pr[j]) - mx)*rs);
    }
    __syncthreads();
    // O = P @ V + bv  (into Qm; Q dead after S)
    mm_tiles(Mq, 4, pch, Pm, 136, VTm, 136, Qm, 72, bv + base, 1.f, wave, ln, qd);
    __syncthreads();
    // out += O @ wo  (B from global pre-transposed woT, stride 512)
    {
      int idx = 0;
      for (int ti = wave; ti < Mq*Mk; ti += 8, ++idx) {
        int mi = ti / Mk, ni = ti - mi*Mk;
        const short* ap = Qm + (mi*16 + ln)*72 + qd*8;
        const short* bp = woT + (long)(ni*16 + ln)*512 + base + qd*8;
        f32x4 acc = accO[idx];
        acc = __builtin_amdgcn_mfma_f32_16x16x32_bf16(*(const short8*)ap,
                                                      *(const short8*)bp, acc, 0,0,0);
        acc = __builtin_amdgcn_mfma_f32_16x16x32_bf16(*(const short8*)(ap+32),
                                                      *(const short8*)(bp+32), acc, 0,0,0);
        accO[idx] = acc;
      }
    }
    __syncthreads();   // Oproj reads of Qm done before next head's builds write it
  }

  // accumulated out-proj -> comb[c][t]
  {
    int idx = 0;
    for (int ti = wave; ti < Mq*Mk; ti += 8, ++idx) {
      int mi = ti / Mk, ni = ti - mi*Mk;
      int col = ni*16 + ln;
      #pragma unroll
      for (int r = 0; r < 4; ++r) {
        int row = mi*16 + qd*4 + r;
        if (row < qrows && col < krows) {
          long off = a ? ((long)row*TT + col) : ((long)col*TT + row);
          atomicAdd(&comb_g[bb + off], accO[idx][r]);
        }
      }
    }
  }
}

// ---------------------------------------------------------------- k_epi
__global__ __launch_bounds__(256) void k_epi(
    const float* __restrict__ comb_g, const float* __restrict__ x,
    const float* __restrict__ st_bo, const float* __restrict__ ts_bo,
    const float* __restrict__ alpha, const float* __restrict__ beta,
    const float* __restrict__ fcw, const float* __restrict__ fcb,
    float* __restrict__ out)
{
  __shared__ float s_cb[CC*CPAD];
  __shared__ float s_w[TT*TT];
  const int b = blockIdx.x, tid = threadIdx.x;
  const long bb = (long)b * (CC*TT);

  for (int o = tid; o < CC*TT; o += 256) {
    int c = o / TT, t = o - c*TT;
    s_cb[c*CPAD + t] = comb_g[bb + o] + st_bo[c] + ts_bo[t];
  }
  for (int o = tid; o < TT*TT; o += 256) {
    int f = o / TT, t = o - f*TT;
    s_w[t*TT + f] = fcw[o];
  }
  __syncthreads();
  if (tid < TT) {
    const int t = tid;
    float mean = 0.f;
    for (int c = 0; c < CC; ++c) mean += s_cb[c*CPAD + t];
    mean *= (1.f/CC);
    float var = 0.f;
    for (int c = 0; c < CC; ++c) { float dv = s_cb[c*CPAD + t] - mean; var += dv*dv; }
    var *= (1.f/CC);
    float rstd = 1.f / sqrtf(var + 1e-5f);
    for (int c = 0; c < CC; ++c) {
      float y = (s_cb[c*CPAD + t] - mean) * rstd * alpha[c] + beta[c];
      s_cb[c*CPAD + t] = y + x[bb + c*TT + t];
    }
  }
  __syncthreads();
  for (int o = tid; o < CC*TT; o += 256) {
    int c = o / TT, f = o - c*TT;
    const float* cr = s_cb + c*CPAD;
    float a0 = 0.f, a1 = 0.f;
    for (int t = 0; t < TT; t += 2) {
      a0 += cr[t    ] * s_w[(t    )*TT + f];
      a1 += cr[t + 1] * s_w[(t + 1)*TT + f];
    }
    out[bb + o] = tanhf(a0 + a1 + fcb[f]);
  }
}

// ---------------------------------------------------------------- R4 fallback
__global__ __launch_bounds__(128) void k_fused(
    const float* __restrict__ x, const float* __restrict__ adj,
    const float* __restrict__ sadj, const float* __restrict__ tmask,
    const float* __restrict__ tadj,
    const float* __restrict__ st_wq, const float* __restrict__ st_bq,
    const float* __restrict__ st_wk, const float* __restrict__ st_bk,
    const float* __restrict__ st_wv, const float* __restrict__ st_bv,
    const float* __restrict__ st_wo, const float* __restrict__ st_bo,
    const float* __restrict__ ts_wq, const float* __restrict__ ts_bq,
    const float* __restrict__ ts_wk, const float* __restrict__ ts_bk,
    const float* __restrict__ ts_wv, const float* __restrict__ ts_bv,
    const float* __restrict__ ts_wo, const float* __restrict__ ts_bo,
    const float* __restrict__ alpha, const float* __restrict__ beta,
    const float* __restrict__ fcw, const float* __restrict__ fcb,
    float* __restrict__ out)
{
  __shared__ float s_sp[CC*TT];
  __shared__ float s_tp[CC*TT];
  __shared__ __align__(16) float s_kv[2*TT*HD];
  __shared__ float s_comb[CC*CPAD];
  __shared__ float s_A[JJ*JJ];
  __shared__ float s_dis[JJ];

  const int b = blockIdx.x, tid = threadIdx.x;
  const long bb = (long)b * (CC*TT);
  float* s_xs = s_comb;
  float* s_Mt = s_kv;

  if (tid < JJ) {
    float dsum = 0.f;
    for (int i = 0; i < JJ; ++i) dsum += adj[tid*JJ + i];
    s_dis[tid] = dsum > 0.f ? rsqrtf(dsum) : 0.f;
  }
  for (int o = tid; o < CC*TT; o += 128) s_xs[o] = x[bb + o];
  for (int o = tid; o < TT*TT; o += 128) {
    int f = o / TT, t = o - f*TT;
    s_Mt[t*TT + f] = tadj[o] * tmask[o];
  }
  __syncthreads();
  for (int o = tid; o < JJ*JJ; o += 128) {
    int v = o / JJ, j = o - v*JJ;
    s_A[o] = sadj[o] * adj[o] * s_dis[v] * s_dis[j];
  }
  __syncthreads();

  for (int o = tid; o < CC*TT; o += 128) {
    int c = o / TT, t = o - c*TT, v = c / 3, dd = c - v*3;
    float acc = 0.f;
    for (int j = 0; j < JJ; ++j) acc += s_A[v*JJ + j] * s_xs[(j*3 + dd)*TT + t];
    s_sp[o] = acc;
  }
  for (int o = tid; o < CC*TT; o += 128) {
    int n = o / TT, f = o - n*TT;
    float a0 = 0.f, a1 = 0.f;
    for (int t = 0; t < TT; t += 2) {
      a0 += s_xs[n*TT + t    ] * s_Mt[(t    )*TT + f];
      a1 += s_xs[n*TT + t + 1] * s_Mt[(t + 1)*TT + f];
    }
    s_tp[o] = a0 + a1;
  }
  __syncthreads();

  for (int o = tid; o < CC*TT; o += 128) {
    int c = o / TT, t = o - c*TT;
    s_comb[c*CPAD + t] = st_bo[c] + ts_bo[t];
  }

  {
    float* s_k = s_kv;
    float* s_v = s_kv + TT*HD;
    for (int h = 0; h < HH; ++h) {
      const int base = h*HD;
      __syncthreads();
      {
        const int d = tid & 63, krow = tid >> 6;
        for (int kk = 0; kk < CC/2; ++kk) {
          int k = kk*2 + krow;
          float aK = st_bk[base + d], aV = st_bv[base + d];
          const float* tr = s_tp + k*TT;
          for (int t = 0; t < TT; ++t) {
            float a = tr[t];
            aK += a * st_wk[(long)t*EE + base + d];
            aV += a * st_wv[(long)t*EE + base + d];
          }
          s_k[k*HD + d] = aK;
          s_v[k*HD + d] = aV;
        }
      }
      __syncthreads();
      if (tid < TT) {
        const int q = tid;
        float qv[HD];
        #pragma unroll
        for (int d = 0; d < HD; ++d) qv[d] = st_bq[base + d];
        for (int c = 0; c < CC; ++c) {
          float a = s_sp[c*TT + q];
          const float* wr = st_wq + (long)c*EE + base;
          #pragma unroll
          for (int d = 0; d < HD; ++d) qv[d] += a * wr[d];
        }
        float m = -INFINITY, l = 0.f, ov[HD];
        #pragma unroll
        for (int d = 0; d < HD; ++d) ov[d] = 0.f;
        for (int k = 0; k < CC; ++k) {
          const float4* kr4 = (const float4*)(s_k + k*HD);
          float s0=0.f,s1=0.f,s2=0.f,s3=0.f;
          #pragma unroll
          for (int i = 0; i < 16; ++i) {
            float4 kk4 = kr4[i];
            s0 += qv[4*i  ]*kk4.x; s1 += qv[4*i+1]*kk4.y;
            s2 += qv[4*i+2]*kk4.z; s3 += qv[4*i+3]*kk4.w;
          }
          float s  = (s0+s1+s2+s3) * 0.125f;
          float mn = fmaxf(m, s);
          float corr = __expf(m - mn);
          float p    = __expf(s - mn);
          l = l*corr + p;
          const float4* vr4 = (const float4*)(s_v + k*HD);
          #pragma unroll
          for (int i = 0; i < 16; ++i) {
            float4 vv4 = vr4[i];
            ov[4*i  ] = ov[4*i  ]*corr + p*vv4.x;
            ov[4*i+1] = ov[4*i+1]*corr + p*vv4.y;
            ov[4*i+2] = ov[4*i+2]*corr + p*vv4.z;
            ov[4*i+3] = ov[4*i+3]*corr + p*vv4.w;
          }
          m = mn;
        }
        float rl = 1.f/l;
        #pragma unroll
        for (int d = 0; d < HD; ++d) ov[d] *= rl;
        for (int c = 0; c < CC; ++c) {
          const float* wr = st_wo + (long)base*CC + c;
          float a0=0.f,a1=0.f,a2=0.f,a3=0.f;
          #pragma unroll
          for (int d = 0; d < HD; d += 4) {
            a0 += ov[d  ]*wr[(long)(d  )*CC]; a1 += ov[d+1]*wr[(long)(d+1)*CC];
            a2 += ov[d+2]*wr[(long)(d+2)*CC]; a3 += ov[d+3]*wr[(long)(d+3)*CC];
          }
          s_comb[c*CPAD + q] += a0+a1+a2+a3;
        }
      }
    }
  }

  {
    float* s_k = s_kv;
    float* s_v = s_kv + TT*HD;
    for (int h = 0; h < HH; ++h) {
      const int base = h*HD;
      __syncthreads();
      {
        const int d = tid & 63, krow = tid >> 6;
        for (int kk = 0; kk < TT/2; ++kk) {
          int k = kk*2 + krow;
          float aK = ts_bk[base + d], aV = ts_bv[base + d];
          for (int c = 0; c < CC; ++c) {
            float a = s_sp[c*TT + k];
            aK += a * ts_wk[(long)c*EE + base + d];
            aV += a * ts_wv[(long)c*EE + base + d];
          }
          s_k[k*HD + d] = aK;
          s_v[k*HD + d] = aV;
        }
      }
      __syncthreads();
      if (tid < CC) {
        const int q = tid;
        float qv[HD];
        #pragma unroll
        for (int d = 0; d < HD; ++d) qv[d] = ts_bq[base + d];
        const float* tr = s_tp + q*TT;
        for (int t = 0; t < TT; ++t) {
          float a = tr[t];
          const float* wr = ts_wq + (long)t*EE + base;
          #pragma unroll
          for (int d = 0; d < HD; ++d) qv[d] += a * wr[d];
        }
        float m = -INFINITY, l = 0.f, ov[HD];
        #pragma unroll
        for (int d = 0; d < HD; ++d) ov[d] = 0.f;
        for (int k = 0; k < TT; ++k) {
          const float4* kr4 = (const float4*)(s_k + k*HD);
          float s0=0.f,s1=0.f,s2=0.f,s3=0.f;
          #pragma unroll
          for (int i = 0; i < 16; ++i) {
            float4 kk4 = kr4[i];
            s0 += qv[4*i  ]*kk4.x; s1 += qv[4*i+1]*kk4.y;
            s2 += qv[4*i+2]*kk4.z; s3 += qv[4*i+3]*kk4.w;
          }
          float s  = (s0+s1+s2+s3) * 0.125f;
          float mn = fmaxf(m, s);
          float corr = __expf(m - mn);
          float p    = __expf(s - mn);
          l = l*corr + p;
          const float4* vr4 = (const float4*)(s_v + k*HD);
          #pragma unroll
          for (int i = 0; i < 16; ++i) {
            float4 vv4 = vr4[i];
            ov[4*i  ] = ov[4*i  ]*corr + p*vv4.x;
            ov[4*i+1] = ov[4*i+1]*corr + p*vv4.y;
            ov[4*i+2] = ov[4*i+2]*corr + p*vv4.z;
            ov[4*i+3] = ov[4*i+3]*corr + p*vv4.w;
          }
          m = mn;
        }
        float rl = 1.f/l;
        #pragma unroll
        for (int d = 0; d < HD; ++d) ov[d] *= rl;
        for (int t = 0; t < TT; ++t) {
          const float* wr = ts_wo + (long)base*TT + t;
          float a0=0.f,a1=0.f,a2=0.f,a3=0.f;
          #pragma unroll
          for (int d = 0; d < HD; d += 4) {
            a0 += ov[d  ]*wr[(long)(d  )*TT]; a1 += ov[d+1]*wr[(long)(d+1)*TT];
            a2 += ov[d+2]*wr[(long)(d+2)*TT]; a3 += ov[d+3]*wr[(long)(d+3)*TT];
          }
          s_comb[q*CPAD + t] += a0+a1+a2+a3;
        }
      }
    }
  }
  __syncthreads();

  if (tid < TT) {
    const int t = tid;
    float mean = 0.f;
    for (int c = 0; c < CC; ++c) mean += s_comb[c*CPAD + t];
    mean *= (1.f/CC);
    float var = 0.f;
    for (int c = 0; c < CC; ++c) { float dv = s_comb[c*CPAD + t] - mean; var += dv*dv; }
    var *= (1.f/CC);
    float rstd = 1.f / sqrtf(var + 1e-5f);
    for (int c = 0; c < CC; ++c) {
      float y = (s_comb[c*CPAD + t] - mean) * rstd * alpha[c] + beta[c];
      s_comb[c*CPAD + t] = y + x[bb + c*TT + t];
    }
  }
  __syncthreads();

  float* s_w = s_kv;
  for (int o = tid; o < TT*TT; o += 128) {
    int f = o / TT, t = o - f*TT;
    s_w[t*TT + f] = fcw[o];
  }
  __syncthreads();

  for (int o = tid; o < CC*TT; o += 128) {
    int c = o / TT, f = o - c*TT;
    const float* cr = s_comb + c*CPAD;
    float a0 = 0.f, a1 = 0.f;
    for (int t = 0; t < TT; t += 2) {
      a0 += cr[t    ] * s_w[(t    )*TT + f];
      a1 += cr[t + 1] * s_w[(t + 1)*TT + f];
    }
    out[bb + o] = tanhf(a0 + a1 + fcb[f]);
  }
}

// ---------------------------------------------------------------- launch
extern "C" void kernel_launch(void* const* d_in, const int* in_sizes, int n_in,
                              void* d_out, int out_size, void* d_ws, size_t ws_size,
                              hipStream_t stream) {
  const float* x     = (const float*)d_in[0];
  const float* adj   = (const float*)d_in[1];
  const float* sadj  = (const float*)d_in[2];
  const float* tmask = (const float*)d_in[3];
  const float* tadj  = (const float*)d_in[4];
  const float* st_wq = (const float*)d_in[5];  const float* st_bq = (const float*)d_in[6];
  const float* st_wk = (const float*)d_in[7];  const float* st_bk = (const float*)d_in[8];
  const float* st_wv = (const float*)d_in[9];  const float* st_bv = (const float*)d_in[10];
  const float* st_wo = (const float*)d_in[11]; const float* st_bo = (const float*)d_in[12];
  const float* ts_wq = (const float*)d_in[13]; const float* ts_bq = (const float*)d_in[14];
  const float* ts_wk = (const float*)d_in[15]; const float* ts_bk = (const float*)d_in[16];
  const float* ts_wv = (const float*)d_in[17]; const float* ts_bv = (const float*)d_in[18];
  const float* ts_wo = (const float*)d_in[19]; const float* ts_bo = (const float*)d_in[20];
  const float* alpha = (const float*)d_in[21]; const float* beta  = (const float*)d_in[22];
  const float* fcw   = (const float*)d_in[23]; const float* fcb   = (const float*)d_in[24];
  float* out = (float*)d_out;

  const int B = in_sizes[0] / (CC*TT);
  const size_t comb_bytes = (size_t)B * CC * TT * 4;
  const size_t w_bytes    = (size_t)W_TOTAL * 2;
  const size_t spt_bytes  = (size_t)B * SPT_R * SPT_S * 2;
  const size_t tp_bytes   = (size_t)B * TP_R * TP_S * 2;
  const size_t need = comb_bytes + w_bytes + spt_bytes + tp_bytes;

  if (ws_size >= need) {
    float* comb_g  = (float*)d_ws;
    bf16*  wsec    = (bf16*)((char*)d_ws + comb_bytes);
    bf16*  spT_all = (bf16*)((char*)d_ws + comb_bytes + w_bytes);
    bf16*  tp_all  = spT_all + (size_t)B * SPT_R * SPT_S;

    hipMemsetAsync(comb_g, 0, comb_bytes, stream);
    // weight pre-transposes (one-off, tiny)
    k_tr<<<(512*128+255)/256, 256, 0, stream>>>(st_wk, wsec + W_STWK, TT, EE, EE, 128);
    k_tr<<<(512*128+255)/256, 256, 0, stream>>>(st_wv, wsec + W_STWV, TT, EE, EE, 128);
    k_tr<<<(512* 96+255)/256, 256, 0, stream>>>(st_wq, wsec + W_STWQ, CC, EE, EE,  96);
    k_tr<<<( 80*512+255)/256, 256, 0, stream>>>(st_wo, wsec + W_STWO, EE, CC,  80, 512);
    k_tr<<<(512* 96+255)/256, 256, 0, stream>>>(ts_wk, wsec + W_TSWK, CC, EE, EE,  96);
    k_tr<<<(512* 96+255)/256, 256, 0, stream>>>(ts_wv, wsec + W_TSWV, CC, EE, EE,  96);
    k_tr<<<(512*128+255)/256, 256, 0, stream>>>(ts_wq, wsec + W_TSWQ, TT, EE, EE, 128);
    k_tr<<<(112*512+255)/256, 256, 0, stream>>>(ts_wo, wsec + W_TSWO, EE, TT, 112, 512);

    k_prep<<<B, 256, 0, stream>>>(x, adj, sadj, tmask, tadj, spT_all, tp_all);
    k_attn<<<B*2, 512, 0, stream>>>(spT_all, tp_all, wsec,
                                    st_bq, st_bv, ts_bq, ts_bv, comb_g);
    k_epi<<<B, 256, 0, stream>>>(comb_g, x, st_bo, ts_bo, alpha, beta, fcw, fcb, out);
  } else {
    k_fused<<<B, 128, 0, stream>>>(x, adj, sadj, tmask, tadj,
                                   st_wq, st_bq, st_wk, st_bk, st_wv, st_bv, st_wo, st_bo,
                                   ts_wq, ts_bq, ts_wk, ts_bk, ts_wv, ts_bv, ts_wo, ts_bo,
                                   alpha, beta, fcw, fcb, out);
  }
}